// Round 9
// baseline (536.312 us; speedup 1.0000x reference)
//
#include <hip/hip_runtime.h>
#include <hip/hip_bf16.h>

// Problem constants (B=8, S=256, D=64, G=32, E=256, L=4, NH=8, DH=8)
constexpr int kB  = 8;
constexpr int kS  = 256;
constexpr int kD  = 64;
constexpr int kG  = 32;
constexpr int kE  = 256;
constexpr int kNH = 8;
constexpr int kHD = 256;              // DH*G = 8*32
constexpr int kDG = kD * kG;          // 2048
constexpr int kT  = kB * kS;          // 2048 tokens
constexpr int kNC = 1000;

using bf16x8 = __attribute__((ext_vector_type(8))) short;
using f32x4  = __attribute__((ext_vector_type(4))) float;

__device__ __forceinline__ short f2bf(float f) {
    unsigned u = __float_as_uint(f);
    unsigned r = (u + 0x7FFFu + ((u >> 16) & 1u)) >> 16;   // RNE
    return (short)r;
}

__device__ __forceinline__ float tanh_fast(float x) {
    float a = fabsf(x);
    float e = __expf(-2.f * a);
    float d = 1.f + e;
    float r = __builtin_amdgcn_rcpf(d);
    r = r * (2.f - d * r);
    float t = (1.f - e) * r;
    return copysignf(t, x);
}

// ---------------- one-time weight fp32->bf16 conversion ----------------
__global__ __launch_bounds__(256) void cvtw_kernel(
    const float* __restrict__ Wq, const float* __restrict__ Wk,
    const float* __restrict__ Wv, const float* __restrict__ Wo,
    const float* __restrict__ W1, const float* __restrict__ W2,
    unsigned short* __restrict__ dst) {
    int idx = (blockIdx.x * 256 + threadIdx.x) * 4;
    const float* src; int off;
    if      (idx <  16384) { src = Wq; off = 0; }
    else if (idx <  32768) { src = Wk; off = 16384; }
    else if (idx <  49152) { src = Wv; off = 32768; }
    else if (idx <  65536) { src = Wo; off = 49152; }
    else if (idx < 131072) { src = W1; off = 65536; }
    else                   { src = W2; off = 131072; }
    const float4 v = *(const float4*)(src + (idx - off));
    *(short4*)&dst[idx] = make_short4(f2bf(v.x), f2bf(v.y), f2bf(v.z), f2bf(v.w));
}

// ---------------- one-time param transpose [R][32] -> [32][R] ---------------
__global__ __launch_bounds__(256) void prep_tr_kernel(
    const float* __restrict__ bq, const float* __restrict__ bk,
    const float* __restrict__ bv, const float* __restrict__ bo,
    const float* __restrict__ b2, const float* __restrict__ gm1,
    const float* __restrict__ gm2, const float* __restrict__ ln2w,
    const float* __restrict__ ln2b, const float* __restrict__ ln1w,
    const float* __restrict__ ln1b, const float* __restrict__ b1,
    float* __restrict__ dst) {
    __shared__ float lt[32 * 257];
    const int a = blockIdx.x >> 2, l = blockIdx.x & 3;
    const float* srcs[12] = {bq, bk, bv, bo, b2, gm1, gm2, ln2w, ln2b, ln1w, ln1b, b1};
    const int R  = (a == 11) ? 256 : 64;
    const int sh = (a == 11) ? 8 : 6;
    const float* src = srcs[a] + (size_t)l * R * 32;
    float* out = dst + a * 8192 + l * R * 32;
    const int tid = threadIdx.x;
    for (int j = tid; j < R * 32; j += 256) lt[(j & 31) * (R + 1) + (j >> 5)] = src[j];
    __syncthreads();
    for (int k = tid; k < R * 32; k += 256) {
        int g = k >> sh, r = k & (R - 1);
        out[k] = lt[g * (R + 1) + r];
    }
}

// ---------------- LN of x_in -> bf16 A (T-layout) + fp32 XT (= x_in^T) -----
__global__ __launch_bounds__(256) void ln_kernel(const float* __restrict__ Xin,
                                                 const float* __restrict__ w,
                                                 const float* __restrict__ b,
                                                 unsigned short* __restrict__ A,
                                                 float* __restrict__ XT) {
    int t = blockIdx.x, tid = threadIdx.x;
    const float* xp = Xin + (size_t)t * kDG;
    __shared__ float r1[256], r2[256];
    __shared__ short st[32 * 72];
    __shared__ float xf[32 * 68];
    float v[8], s = 0.f, ss = 0.f;
#pragma unroll
    for (int j = 0; j < 8; j++) {
        float x = xp[tid + j * 256];
        v[j] = x; s += x; ss += x * x;
        int jj = tid + j * 256;
        xf[(jj & 31) * 68 + (jj >> 5)] = x;
    }
    r1[tid] = s; r2[tid] = ss; __syncthreads();
    for (int o = 128; o > 0; o >>= 1) {
        if (tid < o) { r1[tid] += r1[tid + o]; r2[tid] += r2[tid + o]; }
        __syncthreads();
    }
    float mean = r1[0] * (1.f / kDG);
    float var  = r2[0] * (1.f / kDG) - mean * mean;
    float rstd = rsqrtf(var + 1e-5f);
#pragma unroll
    for (int j = 0; j < 8; j++) {
        int jj = tid + j * 256;                    // jj = d*32 + g
        float val = (v[j] - mean) * rstd * w[jj] + b[jj];
        st[(jj & 31) * 72 + (jj >> 5)] = f2bf(val);
    }
    __syncthreads();
    bf16x8 ov = *(const bf16x8*)&st[(tid >> 3) * 72 + (tid & 7) * 8];
    *(bf16x8*)&A[(size_t)t * kDG + tid * 8] = ov;
    const int row = tid >> 3, col = (tid & 7) * 8;
    float* xo = XT + (size_t)t * kDG + tid * 8;
    *(float4*)(xo + 0) = *(const float4*)&xf[row * 68 + col + 0];
    *(float4*)(xo + 4) = *(const float4*)&xf[row * 68 + col + 4];
}

// ---------------- scalar fp32 versor_linear (X in T-layout) -----------------
__global__ __launch_bounds__(256) void vlinT_kernel(const float* __restrict__ XT,
                                                    const float* __restrict__ W,
                                                    const float* __restrict__ bias,
                                                    float* __restrict__ OutT) {
    __shared__ float sx[32 * 65];
    __shared__ float sw[kD * kD];
    int t = blockIdx.x, tid = threadIdx.x;
    const float* xp = XT + (size_t)t * kDG;
    for (int j = tid; j < kDG; j += 256) sx[(j >> 6) * 65 + (j & 63)] = xp[j];
    for (int j = tid; j < kD * kD; j += 256) sw[j] = W[j];
    __syncthreads();
    int g = tid & 31, ob = tid >> 5;
    int b = t >> 8, s = t & 255;
    float* op = OutT + ((size_t)b * kD * kS + s) * kG;
    for (int o = ob; o < kD; o += 8) {
        float acc = bias[o * kG + g];
        const float* wr = sw + o * kD;
#pragma unroll
        for (int i = 0; i < kD; i++) acc += wr[i] * sx[g * 65 + i];
        op[(size_t)o * kS * kG + g] = acc;
    }
}

// ---------------- MEGA v3: 4 waves per token (unchanged from R8) ----------
template<bool LAST>
__global__ __launch_bounds__(256, 2) void mega_kernel(
    const unsigned short* __restrict__ O,     // attn out bf16 T [tok][g][d]
    const unsigned short* __restrict__ Woh, const float* __restrict__ boT,
    const float* __restrict__ gm1T,
    const float* __restrict__ ln2wT, const float* __restrict__ ln2bT,
    const unsigned short* __restrict__ W1h, const float* __restrict__ b1T,
    const unsigned short* __restrict__ W2h, const float* __restrict__ b2T,
    const float* __restrict__ gm2T,
    const float* __restrict__ ln1wT, const float* __restrict__ ln1bT,
    float* __restrict__ XT,
    const unsigned short* __restrict__ Wqh, const unsigned short* __restrict__ Wkh,
    const unsigned short* __restrict__ Wvh,
    const float* __restrict__ bqT, const float* __restrict__ bkT,
    const float* __restrict__ bvT,
    unsigned short* __restrict__ Q, unsigned short* __restrict__ K,
    unsigned short* __restrict__ V) {
    constexpr int AS = 72;                    // A-tile stride (shorts)
    constexpr int MS = 264;                   // M-tile stride
    __shared__ short sA[32 * AS];             // 4.6 KB  [g][o]
    __shared__ short sM[32 * MS];             // 16.9 KB [g][e]
    __shared__ float sred[8];

    const int tid = threadIdx.x;
    const int w = tid >> 6, lane = tid & 63;
    const int l16 = lane & 15, quad = lane >> 4;
    const int tok = blockIdx.x;
    const size_t tb = (size_t)tok * kDG;
    const int o0 = w * 16 + quad * 4;         // this wave's o window (64-row mats)

    // ---- phase 0: Wo GEMM (1 mt: o rows [w*16, w*16+16)) ----
    float xv[2][4];                           // residual X, carried in regs
    bf16x8 w1f[8];                            // W1 prefetch (4 mt x 2 c)
    {
        const unsigned short* xp = O + tb;
        bf16x8 bfr[2][2];
#pragma unroll
        for (int c = 0; c < 2; ++c)
#pragma unroll
            for (int nt = 0; nt < 2; ++nt)
                bfr[c][nt] = *(const bf16x8*)&xp[(nt * 16 + l16) * kD + c * 32 + quad * 8];

        f32x4 accW[2];
#pragma unroll
        for (int nt = 0; nt < 2; ++nt) accW[nt] = (f32x4){0.f, 0.f, 0.f, 0.f};
#pragma unroll
        for (int c = 0; c < 2; ++c) {
            bf16x8 afr = *(const bf16x8*)&Woh[(w * 16 + l16) * kD + c * 32 + quad * 8];
#pragma unroll
            for (int nt = 0; nt < 2; ++nt)
                accW[nt] = __builtin_amdgcn_mfma_f32_16x16x32_bf16(afr, bfr[c][nt], accW[nt], 0, 0, 0);
        }

#pragma unroll
        for (int mt = 0; mt < 4; ++mt)
#pragma unroll
            for (int c = 0; c < 2; ++c)
                w1f[mt * 2 + c] = *(const bf16x8*)&W1h[((w * 4 + mt) * 16 + l16) * kD + c * 32 + quad * 8];

        // ---- phase 1: residual + mn (X in regs), LN2 -> sA ----
        float s = 0.f, ss = 0.f;
        float vv[2][4];
#pragma unroll
        for (int nt = 0; nt < 2; ++nt) {
            int g = nt * 16 + l16;
            const float4 b4 = *(const float4*)&boT[g * kD + o0];
            const float4 g4 = *(const float4*)&gm1T[g * kD + o0];
            const float4 xi = *(const float4*)&XT[tb + g * kD + o0];
#pragma unroll
            for (int r = 0; r < 4; ++r)
                vv[nt][r] = (&xi.x)[r] + (&g4.x)[r] * (accW[nt][r] + (&b4.x)[r]);
        }
#pragma unroll
        for (int r = 0; r < 4; ++r) {
            float sq = vv[0][r] * vv[0][r] + vv[1][r] * vv[1][r];
#pragma unroll
            for (int off = 1; off < 16; off <<= 1) sq += __shfl_xor(sq, off, 64);
            float rn = 1.f / (sqrtf(sq) + 1e-6f);
#pragma unroll
            for (int nt = 0; nt < 2; ++nt) {
                float x = vv[nt][r] * rn;
                xv[nt][r] = x;
                s += x; ss = fmaf(x, x, ss);
            }
        }
#pragma unroll
        for (int off = 1; off < 64; off <<= 1) {
            s += __shfl_xor(s, off, 64); ss += __shfl_xor(ss, off, 64);
        }
        if (lane == 0) { sred[w] = s; sred[4 + w] = ss; }
        __syncthreads();
        float st = sred[0] + sred[1] + sred[2] + sred[3];
        float sst = sred[4] + sred[5] + sred[6] + sred[7];
        float mean = st * (1.f / kDG);
        float var  = sst * (1.f / kDG) - mean * mean;
        float rstd = rsqrtf(var + 1e-5f);
#pragma unroll
        for (int nt = 0; nt < 2; ++nt) {
            int g = nt * 16 + l16;
            const float4 w4 = *(const float4*)&ln2wT[g * kD + o0];
            const float4 b4 = *(const float4*)&ln2bT[g * kD + o0];
            short4 s4;
#pragma unroll
            for (int r = 0; r < 4; ++r)
                (&s4.x)[r] = f2bf((xv[nt][r] - mean) * rstd * (&w4.x)[r] + (&b4.x)[r]);
            *(short4*)&sA[g * AS + o0] = s4;
        }
    }
    __syncthreads();

    // ---- phase 2: MLP1 (4 mt: e range [w*64, w*64+64)) ----
    bf16x8 w2f[8];                            // W2 prefetch
    {
        bf16x8 afrA[2][2];
#pragma unroll
        for (int c = 0; c < 2; ++c)
#pragma unroll
            for (int nt = 0; nt < 2; ++nt)
                afrA[c][nt] = *(const bf16x8*)&sA[(nt * 16 + l16) * AS + c * 32 + quad * 8];

        f32x4 acc1[4][2];
#pragma unroll
        for (int mt = 0; mt < 4; ++mt)
#pragma unroll
            for (int nt = 0; nt < 2; ++nt) acc1[mt][nt] = (f32x4){0.f, 0.f, 0.f, 0.f};
#pragma unroll
        for (int mt = 0; mt < 4; ++mt)
#pragma unroll
            for (int c = 0; c < 2; ++c)
#pragma unroll
                for (int nt = 0; nt < 2; ++nt)
                    acc1[mt][nt] = __builtin_amdgcn_mfma_f32_16x16x32_bf16(w1f[mt * 2 + c], afrA[c][nt], acc1[mt][nt], 0, 0, 0);

#pragma unroll
        for (int c = 0; c < 8; ++c)
            w2f[c] = *(const bf16x8*)&W2h[(w * 16 + l16) * kE + c * 32 + quad * 8];

#pragma unroll
        for (int mt = 0; mt < 4; ++mt)
#pragma unroll
            for (int nt = 0; nt < 2; ++nt) {
                int g = nt * 16 + l16;
                int e0 = (w * 4 + mt) * 16 + quad * 4;
                const float4 b4 = *(const float4*)&b1T[g * kE + e0];
                short4 s4;
#pragma unroll
                for (int r = 0; r < 4; ++r)
                    (&s4.x)[r] = f2bf(tanh_fast(acc1[mt][nt][r] + (&b4.x)[r]));
                *(short4*)&sM[g * MS + e0] = s4;
            }
    }
    __syncthreads();

    // ---- phase 3: MLP2 (1 mt: o rows [w*16, w*16+16)) ----
    f32x4 acc2[2];
#pragma unroll
    for (int nt = 0; nt < 2; ++nt) acc2[nt] = (f32x4){0.f, 0.f, 0.f, 0.f};
#pragma unroll
    for (int c = 0; c < 8; ++c) {
        bf16x8 bq[2];
#pragma unroll
        for (int nt = 0; nt < 2; ++nt)
            bq[nt] = *(const bf16x8*)&sM[(nt * 16 + l16) * MS + c * 32 + quad * 8];
#pragma unroll
        for (int nt = 0; nt < 2; ++nt)
            acc2[nt] = __builtin_amdgcn_mfma_f32_16x16x32_bf16(w2f[c], bq[nt], acc2[nt], 0, 0, 0);
    }

    bf16x8 wqf[6];
    if constexpr (!LAST) {
        const unsigned short* Wp[3] = {Wqh, Wkh, Wvh};
#pragma unroll
        for (int m = 0; m < 3; ++m)
#pragma unroll
            for (int c = 0; c < 2; ++c)
                wqf[m * 2 + c] = *(const bf16x8*)&Wp[m][(w * 16 + l16) * kD + c * 32 + quad * 8];
    }

    // ---- phase 4: residual(reg) + mn -> XT; LN1(next) -> sA ----
    float yv[2][4];
    float s2 = 0.f, ss2 = 0.f;
    {
        float vv[2][4];
#pragma unroll
        for (int nt = 0; nt < 2; ++nt) {
            int g = nt * 16 + l16;
            const float4 b4 = *(const float4*)&b2T[g * kD + o0];
            const float4 g4 = *(const float4*)&gm2T[g * kD + o0];
#pragma unroll
            for (int r = 0; r < 4; ++r)
                vv[nt][r] = xv[nt][r] + (&g4.x)[r] * (acc2[nt][r] + (&b4.x)[r]);
        }
#pragma unroll
        for (int r = 0; r < 4; ++r) {
            float sq = vv[0][r] * vv[0][r] + vv[1][r] * vv[1][r];
#pragma unroll
            for (int off = 1; off < 16; off <<= 1) sq += __shfl_xor(sq, off, 64);
            float rn = 1.f / (sqrtf(sq) + 1e-6f);
#pragma unroll
            for (int nt = 0; nt < 2; ++nt) {
                float x = vv[nt][r] * rn;
                yv[nt][r] = x;
                s2 += x; ss2 = fmaf(x, x, ss2);
            }
        }
#pragma unroll
        for (int nt = 0; nt < 2; ++nt) {
            int g = nt * 16 + l16;
            float4 xo;
#pragma unroll
            for (int r = 0; r < 4; ++r) (&xo.x)[r] = yv[nt][r];
            *(float4*)&XT[tb + g * kD + o0] = xo;
        }
    }
    if constexpr (LAST) return;

#pragma unroll
    for (int off = 1; off < 64; off <<= 1) {
        s2 += __shfl_xor(s2, off, 64); ss2 += __shfl_xor(ss2, off, 64);
    }
    if (lane == 0) { sred[w] = s2; sred[4 + w] = ss2; }
    __syncthreads();
    {
        float st = sred[0] + sred[1] + sred[2] + sred[3];
        float sst = sred[4] + sred[5] + sred[6] + sred[7];
        float mean = st * (1.f / kDG);
        float var  = sst * (1.f / kDG) - mean * mean;
        float rstd = rsqrtf(var + 1e-5f);
#pragma unroll
        for (int nt = 0; nt < 2; ++nt) {
            int g = nt * 16 + l16;
            const float4 w4 = *(const float4*)&ln1wT[g * kD + o0];
            const float4 b4 = *(const float4*)&ln1bT[g * kD + o0];
            short4 s4;
#pragma unroll
            for (int r = 0; r < 4; ++r)
                (&s4.x)[r] = f2bf((yv[nt][r] - mean) * rstd * (&w4.x)[r] + (&b4.x)[r]);
            *(short4*)&sA[g * AS + o0] = s4;
        }
    }
    __syncthreads();

    // ---- phase 5: QKV(next) from sA with prefetched wqf ----
    {
        bf16x8 afrA[2][2];
#pragma unroll
        for (int c = 0; c < 2; ++c)
#pragma unroll
            for (int nt = 0; nt < 2; ++nt)
                afrA[c][nt] = *(const bf16x8*)&sA[(nt * 16 + l16) * AS + c * 32 + quad * 8];

        const float* Bp[3] = {bqT, bkT, bvT};
        unsigned short* Op[3] = {Q, K, V};
#pragma unroll
        for (int m = 0; m < 3; ++m) {
            f32x4 acc3[2];
#pragma unroll
            for (int nt = 0; nt < 2; ++nt) acc3[nt] = (f32x4){0.f, 0.f, 0.f, 0.f};
#pragma unroll
            for (int c = 0; c < 2; ++c)
#pragma unroll
                for (int nt = 0; nt < 2; ++nt)
                    acc3[nt] = __builtin_amdgcn_mfma_f32_16x16x32_bf16(wqf[m * 2 + c], afrA[c][nt], acc3[nt], 0, 0, 0);
            unsigned short* op = Op[m] + tb;
#pragma unroll
            for (int nt = 0; nt < 2; ++nt) {
                int g = nt * 16 + l16;
                const float4 b4 = *(const float4*)&Bp[m][g * kD + o0];
#pragma unroll
                for (int r = 0; r < 4; ++r)
                    op[(o0 + r) * kG + g] = (unsigned short)f2bf(acc3[nt][r] + (&b4.x)[r]);
            }
        }
    }
}

// ---------------- Q/K/V GEMM for layer 0 only ----------------
__global__ __launch_bounds__(256, 3) void gemm_qkv_kernel(
    const unsigned short* __restrict__ X,
    const unsigned short* __restrict__ Wqh, const unsigned short* __restrict__ Wkh,
    const unsigned short* __restrict__ Wvh,
    const float* __restrict__ bqT, const float* __restrict__ bkT, const float* __restrict__ bvT,
    unsigned short* __restrict__ Q, unsigned short* __restrict__ K, unsigned short* __restrict__ V) {
    constexpr int WS = 64 + 8;
    __shared__ short sW[3 * 64 * WS];

    const int tid = threadIdx.x, wave = tid >> 6, lane = tid & 63;
    const int l16 = lane & 15, quad = lane >> 4;
    const int tok = blockIdx.x * 4 + wave;

    const unsigned short* Wp[3] = {Wqh, Wkh, Wvh};
#pragma unroll
    for (int w = 0; w < 3; ++w)
        for (int j = tid * 8; j < 64 * 64; j += 2048) {
            int o = j >> 6, i = j & 63;
            *(bf16x8*)&sW[w * 64 * WS + o * WS + i] = *(const bf16x8*)(Wp[w] + j);
        }

    const unsigned short* xp = X + (size_t)tok * kDG;
    bf16x8 bfr[2][2];
#pragma unroll
    for (int c = 0; c < 2; ++c)
#pragma unroll
        for (int nt = 0; nt < 2; ++nt)
            bfr[c][nt] = *(const bf16x8*)&xp[(nt * 16 + l16) * kD + c * 32 + quad * 8];
    __syncthreads();

    f32x4 acc[3][4][2];
#pragma unroll
    for (int w = 0; w < 3; ++w)
#pragma unroll
        for (int mt = 0; mt < 4; ++mt)
#pragma unroll
            for (int nt = 0; nt < 2; ++nt) acc[w][mt][nt] = (f32x4){0.f, 0.f, 0.f, 0.f};

#pragma unroll
    for (int w = 0; w < 3; ++w)
#pragma unroll
        for (int mt = 0; mt < 4; ++mt)
#pragma unroll
            for (int c = 0; c < 2; ++c) {
                bf16x8 afr = *(const bf16x8*)&sW[w * 64 * WS + (mt * 16 + l16) * WS + c * 32 + quad * 8];
#pragma unroll
                for (int nt = 0; nt < 2; ++nt)
                    acc[w][mt][nt] = __builtin_amdgcn_mfma_f32_16x16x32_bf16(afr, bfr[c][nt], acc[w][mt][nt], 0, 0, 0);
            }

    unsigned short* Op[3] = {Q, K, V};
    const float* Bp[3] = {bqT, bkT, bvT};
#pragma unroll
    for (int w = 0; w < 3; ++w) {
        unsigned short* op = Op[w] + (size_t)tok * kDG;
#pragma unroll
        for (int mt = 0; mt < 4; ++mt)
#pragma unroll
            for (int nt = 0; nt < 2; ++nt) {
                int g = nt * 16 + l16;
                int o0 = mt * 16 + quad * 4;
                const float4 b4 = *(const float4*)&Bp[w][g * kD + o0];
#pragma unroll
                for (int r = 0; r < 4; ++r)
                    op[(o0 + r) * kG + g] = (unsigned short)f2bf(acc[w][mt][nt][r] + (&b4.x)[r]);
            }
    }
}

// ---------------- MFMA attention v5: key-split flash, 2 waves/SIMD ---------
// 16-row Q tiles, 2 waves/block; wave w owns keys [w*128, w*128+128).
// K (16-key) / V^T (32-key x 128-d) tiles are WAVE-PRIVATE -> no barriers in
// the main loops (same-wave LDS is in-order). 3 barriers/block total.
// 37.9KB LDS -> 4 blocks/CU, grid 1024 -> 8 waves/CU (2/SIMD, 2x R8).
// Partial softmax merged flash-style (exp((m_w-M)*scale) corrections).
constexpr int QS5 = 264;   // Q tile stride
constexpr int PS5 = 136;   // P tile stride (128 keys + 8)
constexpr int VS5 = 40;    // V^T tile stride (32 keys + 8, 16B-aligned rows)

__global__ __launch_bounds__(128) void attn_mfma_kernel(const unsigned short* __restrict__ Q,
                                                        const unsigned short* __restrict__ K,
                                                        const unsigned short* __restrict__ V,
                                                        unsigned short* __restrict__ O) {
    __shared__ short sQ[16 * QS5];           // 8.25 KB (shared Q tile)
    __shared__ short sP[2][16 * PS5];        // 8.5 KB  (per-wave P)
    __shared__ short sV[2][128 * VS5];       // 20 KB   (per-wave K/V tiles; merge overlay)
    __shared__ float sms[2][2][16];

    const int qt = blockIdx.x, h = blockIdx.y, b = blockIdx.z;
    const int tid = threadIdx.x;
    const int w = tid >> 6, lane = tid & 63;
    const int l16 = lane & 15, quad = lane >> 4;
    const size_t bh = (size_t)b * kS * kDG + (size_t)h * kHD;
    const int kb0 = w * 128;                 // this wave's key base

    // stage Q (128 thr, shared) + K tile 0 (wave-private region)
#pragma unroll
    for (int it = 0; it < 4; ++it) {
        int j = it * 1024 + tid * 8;
        int row = j >> 8, col = j & 255;
        *(bf16x8*)&sQ[row * QS5 + col] =
            *(const bf16x8*)(Q + bh + (size_t)(qt * 16 + row) * kDG + col);
    }
    short* kbW = &sV[w][0];                  // K tile [16][QS5] = 4224 shorts <= 5120
#pragma unroll
    for (int it = 0; it < 8; ++it) {
        int j = it * 512 + lane * 8;
        int row = j >> 8, col = j & 255;
        *(bf16x8*)&kbW[row * QS5 + col] =
            *(const bf16x8*)(K + bh + (size_t)(kb0 + row) * kDG + col);
    }
    __syncthreads();                          // barrier 1: Q visible to both waves

    bf16x8 afrag[8];
#pragma unroll
    for (int c = 0; c < 8; ++c)
        afrag[c] = *(const bf16x8*)&sQ[l16 * QS5 + c * 32 + quad * 8];

    f32x4 acc[8];
#pragma unroll
    for (int i = 0; i < 8; ++i) acc[i] = (f32x4){0.f, 0.f, 0.f, 0.f};

    // QK^T over this wave's 128 keys, 16-key tiles, single private buffer
    for (int kt = 0; kt < 8; ++kt) {
        bf16x8 kpre[8];
        if (kt < 7) {
#pragma unroll
            for (int it = 0; it < 8; ++it) {
                int j = it * 512 + lane * 8;
                int row = j >> 8, col = j & 255;
                kpre[it] = *(const bf16x8*)(K + bh + (size_t)(kb0 + (kt + 1) * 16 + row) * kDG + col);
            }
        }
        f32x4 a = acc[kt];
#pragma unroll
        for (int c = 0; c < 8; ++c) {
            bf16x8 bfrag = *(const bf16x8*)&kbW[l16 * QS5 + c * 32 + quad * 8];
            a = __builtin_amdgcn_mfma_f32_16x16x32_bf16(afrag[c], bfrag, a, 0, 0, 0);
        }
        acc[kt] = a;
        if (kt < 7) {
#pragma unroll
            for (int it = 0; it < 8; ++it) {
                int j = it * 512 + lane * 8;
                int row = j >> 8, col = j & 255;
                *(bf16x8*)&kbW[row * QS5 + col] = kpre[it];
            }
        }
    }

    // partial softmax (this wave's 128 keys); rows = quad*4 + r
    float mw[4], sw[4];
#pragma unroll
    for (int r = 0; r < 4; ++r) {
        float m = -1e30f;
#pragma unroll
        for (int t = 0; t < 8; ++t) m = fmaxf(m, acc[t][r]);
#pragma unroll
        for (int off = 1; off < 16; off <<= 1) m = fmaxf(m, __shfl_xor(m, off, 16));
        float s = 0.f;
#pragma unroll
        for (int t = 0; t < 8; ++t) {
            float p = __expf((acc[t][r] - m) * 0.0625f);
            acc[t][r] = p; s += p;
        }
#pragma unroll
        for (int off = 1; off < 16; off <<= 1) s += __shfl_xor(s, off, 16);
        mw[r] = m; sw[r] = s;
    }

    // P (bf16) into this wave's private sP
    short* sPw = &sP[w][0];
#pragma unroll
    for (int t = 0; t < 8; ++t)
#pragma unroll
        for (int r = 0; r < 4; ++r)
            sPw[(quad * 4 + r) * PS5 + t * 16 + l16] = f2bf(acc[t][r]);

    // PV: V^T tiles [128 d][32 keys], wave-private, gather-transpose staging
    short* vbW = &sV[w][0];
    const int k4 = lane >> 3, dseg = (lane & 7) * 16;
    {   // stage tile 0 (dh=0, vt=0)
        short4 vr[4][4];
#pragma unroll
        for (int r = 0; r < 4; ++r)
#pragma unroll
            for (int i = 0; i < 4; ++i)
                vr[r][i] = *(const short4*)(V + bh + (size_t)(kb0 + k4 * 4 + r) * kDG + dseg + i * 4);
#pragma unroll
        for (int i = 0; i < 16; ++i) {
            short4 p4 = make_short4((&vr[0][i >> 2].x)[i & 3], (&vr[1][i >> 2].x)[i & 3],
                                    (&vr[2][i >> 2].x)[i & 3], (&vr[3][i >> 2].x)[i & 3]);
            *(short4*)&vbW[(dseg + i) * VS5 + k4 * 4] = p4;
        }
    }

    f32x4 oacc[16];
#pragma unroll
    for (int i = 0; i < 16; ++i) oacc[i] = (f32x4){0.f, 0.f, 0.f, 0.f};

    for (int t = 0; t < 8; ++t) {
        const int dh = t >> 2, vt = t & 3;
        short4 vpre[4][4];
        if (t < 7) {
            const int nt_ = t + 1, ndh = nt_ >> 2, nvt = nt_ & 3;
#pragma unroll
            for (int r = 0; r < 4; ++r)
#pragma unroll
                for (int i = 0; i < 4; ++i)
                    vpre[r][i] = *(const short4*)(V + bh + (size_t)(kb0 + nvt * 32 + k4 * 4 + r) * kDG + ndh * 128 + dseg + i * 4);
        }
        bf16x8 pfrag = *(const bf16x8*)&sPw[l16 * PS5 + vt * 32 + quad * 8];
#pragma unroll
        for (int dt = 0; dt < 8; ++dt) {
            bf16x8 vfrag = *(const bf16x8*)&vbW[(dt * 16 + l16) * VS5 + quad * 8];
            oacc[dh * 8 + dt] = __builtin_amdgcn_mfma_f32_16x16x32_bf16(pfrag, vfrag, oacc[dh * 8 + dt], 0, 0, 0);
        }
        if (t < 7) {
#pragma unroll
            for (int i = 0; i < 16; ++i) {
                short4 p4 = make_short4((&vpre[0][i >> 2].x)[i & 3], (&vpre[1][i >> 2].x)[i & 3],
                                        (&vpre[2][i >> 2].x)[i & 3], (&vpre[3][i >> 2].x)[i & 3]);
                *(short4*)&vbW[(dseg + i) * VS5 + k4 * 4] = p4;
            }
        }
    }

    // flash merge across the two key-halves
    if (l16 == 0) {
#pragma unroll
        for (int r = 0; r < 4; ++r) {
            sms[w][0][quad * 4 + r] = mw[r];
            sms[w][1][quad * 4 + r] = sw[r];
        }
    }
    __syncthreads();                          // barrier 2: m/s visible; V regions free

    float cs[4], inv[4];
#pragma unroll
    for (int r = 0; r < 4; ++r) {
        float mo = sms[1 - w][0][quad * 4 + r];
        float so = sms[1 - w][1][quad * 4 + r];
        float M = fmaxf(mw[r], mo);
        cs[r] = __expf((mw[r] - M) * 0.0625f);
        float co = __expf((mo - M) * 0.0625f);
        inv[r] = 1.f / (sw[r] * cs[r] + so * co);
    }

    float* mbuf = (float*)&sV[0][0];          // [16][260] fp32 overlay (16.6KB <= 20KB)
    if (w == 1) {
#pragma unroll
        for (int od = 0; od < 16; ++od) {
            int d = (od >> 3) * 128 + (od & 7) * 16 + l16;
#pragma unroll
            for (int r = 0; r < 4; ++r)
                mbuf[(quad * 4 + r) * 260 + d] = oacc[od][r] * cs[r];
        }
    }
    __syncthreads();                          // barrier 3

    if (w == 0) {
        // O write: bf16 T-layout [tok][g*64 + h*8 + dl]
        const size_t ob = (size_t)(b * kS + qt * 16 + quad * 4) * kDG + h * 8;
#pragma unroll
        for (int gg = 0; gg < 2; ++gg) {
            int g = gg * 16 + l16;
#pragma unroll
            for (int r = 0; r < 4; ++r) {
                bf16x8 pk;
#pragma unroll
                for (int k = 0; k < 8; ++k) {
                    int od = (k >> 2) * 8 + (k & 3) * 2 + gg;
                    int d = (od >> 3) * 128 + (od & 7) * 16 + l16;
                    float mrg = oacc[od][r] * cs[r] + mbuf[(quad * 4 + r) * 260 + d];
                    pk[k] = f2bf(mrg * inv[r]);
                }
                *(bf16x8*)&O[ob + (size_t)r * kDG + g * kD] = pk;
            }
        }
    }
}

// ---------------- in-thread geometric product with compile-time signs -------
constexpr int pc_ce(unsigned v) { int c = 0; while (v) { c += v & 1; v >>= 1; } return c; }
constexpr unsigned gp_mask_ce(int a) {
    unsigned m = 0;
    for (int c = 0; c < 32; ++c) {
        int b = a ^ c;
        int s = (a & b) >> 4;
        for (int t = a >> 1; t; t >>= 1) s += pc_ce(t & b);
        if (s & 1) m |= (1u << c);
    }
    return m;
}

template<int A>
__device__ __forceinline__ void gp_term(const float* x, const float* y, float* acc) {
    constexpr unsigned m = gp_mask_ce(A);
    const float xa = x[A], nxa = -xa;
#pragma unroll
    for (int c = 0; c < 32; ++c)
        acc[c] = fmaf(((m >> c) & 1u) ? nxa : xa, y[A ^ c], acc[c]);
}

__device__ __forceinline__ void gp_mn_t(const float* x, const float* y, float* out) {
    float acc[32];
#pragma unroll
    for (int c = 0; c < 32; ++c) acc[c] = 0.f;
    gp_term<0>(x, y, acc);  gp_term<1>(x, y, acc);  gp_term<2>(x, y, acc);  gp_term<3>(x, y, acc);
    gp_term<4>(x, y, acc);  gp_term<5>(x, y, acc);  gp_term<6>(x, y, acc);  gp_term<7>(x, y, acc);
    gp_term<8>(x, y, acc);  gp_term<9>(x, y, acc);  gp_term<10>(x, y, acc); gp_term<11>(x, y, acc);
    gp_term<12>(x, y, acc); gp_term<13>(x, y, acc); gp_term<14>(x, y, acc); gp_term<15>(x, y, acc);
    gp_term<16>(x, y, acc); gp_term<17>(x, y, acc); gp_term<18>(x, y, acc); gp_term<19>(x, y, acc);
    gp_term<20>(x, y, acc); gp_term<21>(x, y, acc); gp_term<22>(x, y, acc); gp_term<23>(x, y, acc);
    gp_term<24>(x, y, acc); gp_term<25>(x, y, acc); gp_term<26>(x, y, acc); gp_term<27>(x, y, acc);
    gp_term<28>(x, y, acc); gp_term<29>(x, y, acc); gp_term<30>(x, y, acc); gp_term<31>(x, y, acc);
    float ss = 0.f;
#pragma unroll
    for (int c = 0; c < 32; ++c) ss = fmaf(acc[c], acc[c], ss);
    float r = 1.f / (sqrtf(ss) + 1e-6f);
#pragma unroll
    for (int c = 0; c < 32; ++c) out[c] = acc[c] * r;
}

__device__ __forceinline__ void leaf_load(const float* base, float* v) {
#pragma unroll
    for (int i = 0; i < 8; ++i) {
        const float4 f = *(const float4*)(base + i * 4);
        v[i * 4 + 0] = 0.5f * f.x; v[i * 4 + 1] = 0.5f * f.y;
        v[i * 4 + 2] = 0.5f * f.z; v[i * 4 + 3] = 0.5f * f.w;
    }
    v[0] += 1.f;
    float ss = 0.f;
#pragma unroll
    for (int c = 0; c < 32; ++c) ss = fmaf(v[c], v[c], ss);
    float r = 1.f / (sqrtf(ss) + 1e-6f);
#pragma unroll
    for (int c = 0; c < 32; ++c) v[c] *= r;
}

// ---------------- scan: 1 wave per sequence, 1 block per wave ---------------
// 512 blocks spread over 256 CUs (was 128 blocks on half the chip).
__global__ __launch_bounds__(64) void scanreg_kernel(const float* __restrict__ DT,
                                                     float* __restrict__ pooled) {
    const int lane = threadIdx.x & 63;
    const int seq = blockIdx.x;
    const float* base = DT + ((size_t)seq * kS + lane * 4) * kG;

    float R[32], Y[32], P[32], Xa[32], Yb[32];

    leaf_load(base, R);
    for (int j = 1; j < 4; ++j) {
        leaf_load(base + j * kG, Y);
        gp_mn_t(Y, R, R);
    }

    for (int step = 1; step < 64; step <<= 1) {
        const bool up = lane & step;
#pragma unroll
        for (int c = 0; c < 32; ++c) P[c] = __shfl_xor(R[c], step, 64);
#pragma unroll
        for (int c = 0; c < 32; ++c) {
            Xa[c] = up ? R[c] : P[c];
            Yb[c] = up ? P[c] : R[c];
        }
        gp_mn_t(Xa, Yb, R);
    }

    if (lane == 0) {
        float* op = pooled + (size_t)seq * kG;
#pragma unroll
        for (int i = 0; i < 8; ++i)
            *(float4*)(op + i * 4) = make_float4(R[i * 4], R[i * 4 + 1], R[i * 4 + 2], R[i * 4 + 3]);
    }
}

// ---------------- classifier ----------------
__global__ __launch_bounds__(256) void cls2_kernel(const float* __restrict__ P,
                                                   const float* __restrict__ Wc,
                                                   const float* __restrict__ bc,
                                                   float* __restrict__ out) {
    __shared__ float sp[kB * kDG];
    const int tid = threadIdx.x, wave = tid >> 6, lane = tid & 63;
    for (int j = tid * 4; j < kB * kDG; j += 1024)
        *(float4*)&sp[j] = *(const float4*)(P + j);
    __syncthreads();

    const int c = blockIdx.x * 4 + wave;
    const float* w = Wc + (size_t)c * kDG;
    float acc[kB];
#pragma unroll
    for (int b = 0; b < kB; ++b) acc[b] = 0.f;
#pragma unroll
    for (int cc = 0; cc < 8; ++cc) {
        const float4 w4 = *(const float4*)(w + cc * 256 + lane * 4);
#pragma unroll
        for (int b = 0; b < kB; ++b) {
            const float4 p4 = *(const float4*)&sp[b * kDG + cc * 256 + lane * 4];
            acc[b] += w4.x * p4.x + w4.y * p4.y + w4.z * p4.z + w4.w * p4.w;
        }
    }
#pragma unroll
    for (int b = 0; b < kB; ++b)
#pragma unroll
        for (int off = 32; off > 0; off >>= 1) acc[b] += __shfl_xor(acc[b], off, 64);
    if (lane == 0) {
        float bias = bc[c];
#pragma unroll
        for (int b = 0; b < kB; ++b) out[b * kNC + c] = acc[b] + bias;
    }
}

extern "C" void kernel_launch(void* const* d_in, const int* in_sizes, int n_in,
                              void* d_out, int out_size, void* d_ws, size_t ws_size,
                              hipStream_t stream) {
    const float* x_in = (const float*)d_in[0];
    const float* Wq   = (const float*)d_in[1];
    const float* bq   = (const float*)d_in[2];
    const float* Wk   = (const float*)d_in[3];
    const float* bk   = (const float*)d_in[4];
    const float* Wv   = (const float*)d_in[5];
    const float* bv   = (const float*)d_in[6];
    const float* Wo   = (const float*)d_in[7];
    const float* bo   = (const float*)d_in[8];
    const float* ln1w = (const float*)d_in[9];
    const float* ln1b = (const float*)d_in[10];
    const float* ln2w = (const float*)d_in[11];
    const float* ln2b = (const float*)d_in[12];
    const float* gm1  = (const float*)d_in[13];
    const float* gm2  = (const float*)d_in[14];
    const float* W1   = (const float*)d_in[15];
    const float* b1   = (const float*)d_in[16];
    const float* W2   = (const float*)d_in[17];
    const float* b2   = (const float*)d_in[18];
    const float* Wr   = (const float*)d_in[19];
    const float* br   = (const float*)d_in[20];
    const float* Wc   = (const float*)d_in[21];
    const float* bc   = (const float*)d_in[22];

    const size_t NEL = (size_t)kT * kDG;
    float* F  = (float*)d_ws;
    float* XT = F;                                   // region 0: fp32 residual, T-layout
    unsigned short* Abf = (unsigned short*)(F + NEL);// region 1: attn in (A) / attn out (O)
    unsigned short* Qh = (unsigned short*)(F + 2 * NEL);
    unsigned short* Kh = (unsigned short*)(F + 3 * NEL);
    unsigned short* Vh = (unsigned short*)(F + 4 * NEL);
    unsigned short* Wb = (unsigned short*)(F + 5 * NEL);   // bf16 weights (384 KB)
    float* PT = F + 3 * NEL + NEL / 2;               // T-params (480 KB, gap after Kh)
    float* pooled = F + 2 * NEL;
    float* DT = F + NEL;

    cvtw_kernel<<<192, 256, 0, stream>>>(Wq, Wk, Wv, Wo, W1, W2, Wb);
    prep_tr_kernel<<<48, 256, 0, stream>>>(bq, bk, bv, bo, b2, gm1, gm2,
                                           ln2w, ln2b, ln1w, ln1b, b1, PT);
    unsigned short* Wqh = Wb;
    unsigned short* Wkh = Wb + 16384;
    unsigned short* Wvh = Wb + 32768;
    unsigned short* Woh = Wb + 49152;
    unsigned short* W1h = Wb + 65536;
    unsigned short* W2h = Wb + 131072;

    auto bqT   = [&](int l) { return PT + 0     + l * 2048; };
    auto bkT   = [&](int l) { return PT + 8192  + l * 2048; };
    auto bvT   = [&](int l) { return PT + 16384 + l * 2048; };
    auto boT   = [&](int l) { return PT + 24576 + l * 2048; };
    auto b2T   = [&](int l) { return PT + 32768 + l * 2048; };
    auto gm1T  = [&](int l) { return PT + 40960 + l * 2048; };
    auto gm2T  = [&](int l) { return PT + 49152 + l * 2048; };
    auto ln2wT = [&](int l) { return PT + 57344 + l * 2048; };
    auto ln2bT = [&](int l) { return PT + 65536 + l * 2048; };
    auto ln1wT = [&](int l) { return PT + 73728 + l * 2048; };
    auto ln1bT = [&](int l) { return PT + 81920 + l * 2048; };
    auto b1T   = [&](int l) { return PT + 90112 + l * 8192; };

    ln_kernel<<<kT, 256, 0, stream>>>(x_in, ln1w, ln1b, Abf, XT);
    gemm_qkv_kernel<<<kT / 4, 256, 0, stream>>>(Abf,
        Wqh, Wkh, Wvh, bqT(0), bkT(0), bvT(0), Qh, Kh, Vh);

    for (int l = 0; l < 4; l++) {
        attn_mfma_kernel<<<dim3(16, kNH, kB), 128, 0, stream>>>(Qh, Kh, Vh, Abf);
        if (l < 3)
            mega_kernel<false><<<kT, 256, 0, stream>>>(Abf,
                Woh + l * 4096, boT(l), gm1T(l), ln2wT(l), ln2bT(l),
                W1h + l * 16384, b1T(l), W2h + l * 16384, b2T(l), gm2T(l),
                ln1wT(l + 1), ln1bT(l + 1), XT,
                Wqh + (l + 1) * 4096, Wkh + (l + 1) * 4096, Wvh + (l + 1) * 4096,
                bqT(l + 1), bkT(l + 1), bvT(l + 1), Qh, Kh, Vh);
        else
            mega_kernel<true><<<kT, 256, 0, stream>>>(Abf,
                Woh + l * 4096, boT(l), gm1T(l), ln2wT(l), ln2bT(l),
                W1h + l * 16384, b1T(l), W2h + l * 16384, b2T(l), gm2T(l),
                nullptr, nullptr, XT,
                nullptr, nullptr, nullptr, nullptr, nullptr, nullptr,
                nullptr, nullptr, nullptr);
    }

    vlinT_kernel<<<kT, 256, 0, stream>>>(XT, Wr, br, DT);
    scanreg_kernel<<<kB * kD, 64, 0, stream>>>(DT, pooled);
    cls2_kernel<<<kNC / 4, 256, 0, stream>>>(pooled, Wc, bc, (float*)d_out);
}

// Round 10
// 533.771 us; speedup vs baseline: 1.0048x; 1.0048x over previous
//
#include <hip/hip_runtime.h>
#include <hip/hip_bf16.h>

// Problem constants (B=8, S=256, D=64, G=32, E=256, L=4, NH=8, DH=8)
constexpr int kB  = 8;
constexpr int kS  = 256;
constexpr int kD  = 64;
constexpr int kG  = 32;
constexpr int kE  = 256;
constexpr int kNH = 8;
constexpr int kHD = 256;              // DH*G = 8*32
constexpr int kDG = kD * kG;          // 2048
constexpr int kT  = kB * kS;          // 2048 tokens
constexpr int kNC = 1000;

using bf16x8 = __attribute__((ext_vector_type(8))) short;
using f32x4  = __attribute__((ext_vector_type(4))) float;

__device__ __forceinline__ short f2bf(float f) {
    unsigned u = __float_as_uint(f);
    unsigned r = (u + 0x7FFFu + ((u >> 16) & 1u)) >> 16;   // RNE
    return (short)r;
}

__device__ __forceinline__ float tanh_fast(float x) {
    float a = fabsf(x);
    float e = __expf(-2.f * a);
    float d = 1.f + e;
    float r = __builtin_amdgcn_rcpf(d);
    r = r * (2.f - d * r);
    float t = (1.f - e) * r;
    return copysignf(t, x);
}

// ---------------- one-time weight fp32->bf16 conversion ----------------
__global__ __launch_bounds__(256) void cvtw_kernel(
    const float* __restrict__ Wq, const float* __restrict__ Wk,
    const float* __restrict__ Wv, const float* __restrict__ Wo,
    const float* __restrict__ W1, const float* __restrict__ W2,
    unsigned short* __restrict__ dst) {
    int idx = (blockIdx.x * 256 + threadIdx.x) * 4;
    const float* src; int off;
    if      (idx <  16384) { src = Wq; off = 0; }
    else if (idx <  32768) { src = Wk; off = 16384; }
    else if (idx <  49152) { src = Wv; off = 32768; }
    else if (idx <  65536) { src = Wo; off = 49152; }
    else if (idx < 131072) { src = W1; off = 65536; }
    else                   { src = W2; off = 131072; }
    const float4 v = *(const float4*)(src + (idx - off));
    *(short4*)&dst[idx] = make_short4(f2bf(v.x), f2bf(v.y), f2bf(v.z), f2bf(v.w));
}

// ---------------- one-time param transpose [R][32] -> [32][R] ---------------
__global__ __launch_bounds__(256) void prep_tr_kernel(
    const float* __restrict__ bq, const float* __restrict__ bk,
    const float* __restrict__ bv, const float* __restrict__ bo,
    const float* __restrict__ b2, const float* __restrict__ gm1,
    const float* __restrict__ gm2, const float* __restrict__ ln2w,
    const float* __restrict__ ln2b, const float* __restrict__ ln1w,
    const float* __restrict__ ln1b, const float* __restrict__ b1,
    float* __restrict__ dst) {
    __shared__ float lt[32 * 257];
    const int a = blockIdx.x >> 2, l = blockIdx.x & 3;
    const float* srcs[12] = {bq, bk, bv, bo, b2, gm1, gm2, ln2w, ln2b, ln1w, ln1b, b1};
    const int R  = (a == 11) ? 256 : 64;
    const int sh = (a == 11) ? 8 : 6;
    const float* src = srcs[a] + (size_t)l * R * 32;
    float* out = dst + a * 8192 + l * R * 32;
    const int tid = threadIdx.x;
    for (int j = tid; j < R * 32; j += 256) lt[(j & 31) * (R + 1) + (j >> 5)] = src[j];
    __syncthreads();
    for (int k = tid; k < R * 32; k += 256) {
        int g = k >> sh, r = k & (R - 1);
        out[k] = lt[g * (R + 1) + r];
    }
}

// ---------------- LN of x_in -> bf16 A (T-layout) + fp32 XT (= x_in^T) -----
__global__ __launch_bounds__(256) void ln_kernel(const float* __restrict__ Xin,
                                                 const float* __restrict__ w,
                                                 const float* __restrict__ b,
                                                 unsigned short* __restrict__ A,
                                                 float* __restrict__ XT) {
    int t = blockIdx.x, tid = threadIdx.x;
    const float* xp = Xin + (size_t)t * kDG;
    __shared__ float r1[256], r2[256];
    __shared__ short st[32 * 72];
    __shared__ float xf[32 * 68];
    float v[8], s = 0.f, ss = 0.f;
#pragma unroll
    for (int j = 0; j < 8; j++) {
        float x = xp[tid + j * 256];
        v[j] = x; s += x; ss += x * x;
        int jj = tid + j * 256;
        xf[(jj & 31) * 68 + (jj >> 5)] = x;
    }
    r1[tid] = s; r2[tid] = ss; __syncthreads();
    for (int o = 128; o > 0; o >>= 1) {
        if (tid < o) { r1[tid] += r1[tid + o]; r2[tid] += r2[tid + o]; }
        __syncthreads();
    }
    float mean = r1[0] * (1.f / kDG);
    float var  = r2[0] * (1.f / kDG) - mean * mean;
    float rstd = rsqrtf(var + 1e-5f);
#pragma unroll
    for (int j = 0; j < 8; j++) {
        int jj = tid + j * 256;                    // jj = d*32 + g
        float val = (v[j] - mean) * rstd * w[jj] + b[jj];
        st[(jj & 31) * 72 + (jj >> 5)] = f2bf(val);
    }
    __syncthreads();
    bf16x8 ov = *(const bf16x8*)&st[(tid >> 3) * 72 + (tid & 7) * 8];
    *(bf16x8*)&A[(size_t)t * kDG + tid * 8] = ov;
    const int row = tid >> 3, col = (tid & 7) * 8;
    float* xo = XT + (size_t)t * kDG + tid * 8;
    *(float4*)(xo + 0) = *(const float4*)&xf[row * 68 + col + 0];
    *(float4*)(xo + 4) = *(const float4*)&xf[row * 68 + col + 4];
}

// ---------------- scalar fp32 versor_linear (X in T-layout) -----------------
__global__ __launch_bounds__(256) void vlinT_kernel(const float* __restrict__ XT,
                                                    const float* __restrict__ W,
                                                    const float* __restrict__ bias,
                                                    float* __restrict__ OutT) {
    __shared__ float sx[32 * 65];
    __shared__ float sw[kD * kD];
    int t = blockIdx.x, tid = threadIdx.x;
    const float* xp = XT + (size_t)t * kDG;
    for (int j = tid; j < kDG; j += 256) sx[(j >> 6) * 65 + (j & 63)] = xp[j];
    for (int j = tid; j < kD * kD; j += 256) sw[j] = W[j];
    __syncthreads();
    int g = tid & 31, ob = tid >> 5;
    int b = t >> 8, s = t & 255;
    float* op = OutT + ((size_t)b * kD * kS + s) * kG;
    for (int o = ob; o < kD; o += 8) {
        float acc = bias[o * kG + g];
        const float* wr = sw + o * kD;
#pragma unroll
        for (int i = 0; i < kD; i++) acc += wr[i] * sx[g * 65 + i];
        op[(size_t)o * kS * kG + g] = acc;
    }
}

// ---------------- MEGA v3: 4 waves per token (unchanged from R8) ----------
template<bool LAST>
__global__ __launch_bounds__(256, 2) void mega_kernel(
    const unsigned short* __restrict__ O,     // attn out bf16 T [tok][g][d]
    const unsigned short* __restrict__ Woh, const float* __restrict__ boT,
    const float* __restrict__ gm1T,
    const float* __restrict__ ln2wT, const float* __restrict__ ln2bT,
    const unsigned short* __restrict__ W1h, const float* __restrict__ b1T,
    const unsigned short* __restrict__ W2h, const float* __restrict__ b2T,
    const float* __restrict__ gm2T,
    const float* __restrict__ ln1wT, const float* __restrict__ ln1bT,
    float* __restrict__ XT,
    const unsigned short* __restrict__ Wqh, const unsigned short* __restrict__ Wkh,
    const unsigned short* __restrict__ Wvh,
    const float* __restrict__ bqT, const float* __restrict__ bkT,
    const float* __restrict__ bvT,
    unsigned short* __restrict__ Q, unsigned short* __restrict__ K,
    unsigned short* __restrict__ V) {
    constexpr int AS = 72;                    // A-tile stride (shorts)
    constexpr int MS = 264;                   // M-tile stride
    __shared__ short sA[32 * AS];             // 4.6 KB  [g][o]
    __shared__ short sM[32 * MS];             // 16.9 KB [g][e]
    __shared__ float sred[8];

    const int tid = threadIdx.x;
    const int w = tid >> 6, lane = tid & 63;
    const int l16 = lane & 15, quad = lane >> 4;
    const int tok = blockIdx.x;
    const size_t tb = (size_t)tok * kDG;
    const int o0 = w * 16 + quad * 4;         // this wave's o window (64-row mats)

    // ---- phase 0: Wo GEMM (1 mt: o rows [w*16, w*16+16)) ----
    float xv[2][4];                           // residual X, carried in regs
    bf16x8 w1f[8];                            // W1 prefetch (4 mt x 2 c)
    {
        const unsigned short* xp = O + tb;
        bf16x8 bfr[2][2];
#pragma unroll
        for (int c = 0; c < 2; ++c)
#pragma unroll
            for (int nt = 0; nt < 2; ++nt)
                bfr[c][nt] = *(const bf16x8*)&xp[(nt * 16 + l16) * kD + c * 32 + quad * 8];

        f32x4 accW[2];
#pragma unroll
        for (int nt = 0; nt < 2; ++nt) accW[nt] = (f32x4){0.f, 0.f, 0.f, 0.f};
#pragma unroll
        for (int c = 0; c < 2; ++c) {
            bf16x8 afr = *(const bf16x8*)&Woh[(w * 16 + l16) * kD + c * 32 + quad * 8];
#pragma unroll
            for (int nt = 0; nt < 2; ++nt)
                accW[nt] = __builtin_amdgcn_mfma_f32_16x16x32_bf16(afr, bfr[c][nt], accW[nt], 0, 0, 0);
        }

#pragma unroll
        for (int mt = 0; mt < 4; ++mt)
#pragma unroll
            for (int c = 0; c < 2; ++c)
                w1f[mt * 2 + c] = *(const bf16x8*)&W1h[((w * 4 + mt) * 16 + l16) * kD + c * 32 + quad * 8];

        // ---- phase 1: residual + mn (X in regs), LN2 -> sA ----
        float s = 0.f, ss = 0.f;
        float vv[2][4];
#pragma unroll
        for (int nt = 0; nt < 2; ++nt) {
            int g = nt * 16 + l16;
            const float4 b4 = *(const float4*)&boT[g * kD + o0];
            const float4 g4 = *(const float4*)&gm1T[g * kD + o0];
            const float4 xi = *(const float4*)&XT[tb + g * kD + o0];
#pragma unroll
            for (int r = 0; r < 4; ++r)
                vv[nt][r] = (&xi.x)[r] + (&g4.x)[r] * (accW[nt][r] + (&b4.x)[r]);
        }
#pragma unroll
        for (int r = 0; r < 4; ++r) {
            float sq = vv[0][r] * vv[0][r] + vv[1][r] * vv[1][r];
#pragma unroll
            for (int off = 1; off < 16; off <<= 1) sq += __shfl_xor(sq, off, 64);
            float rn = 1.f / (sqrtf(sq) + 1e-6f);
#pragma unroll
            for (int nt = 0; nt < 2; ++nt) {
                float x = vv[nt][r] * rn;
                xv[nt][r] = x;
                s += x; ss = fmaf(x, x, ss);
            }
        }
#pragma unroll
        for (int off = 1; off < 64; off <<= 1) {
            s += __shfl_xor(s, off, 64); ss += __shfl_xor(ss, off, 64);
        }
        if (lane == 0) { sred[w] = s; sred[4 + w] = ss; }
        __syncthreads();
        float st = sred[0] + sred[1] + sred[2] + sred[3];
        float sst = sred[4] + sred[5] + sred[6] + sred[7];
        float mean = st * (1.f / kDG);
        float var  = sst * (1.f / kDG) - mean * mean;
        float rstd = rsqrtf(var + 1e-5f);
#pragma unroll
        for (int nt = 0; nt < 2; ++nt) {
            int g = nt * 16 + l16;
            const float4 w4 = *(const float4*)&ln2wT[g * kD + o0];
            const float4 b4 = *(const float4*)&ln2bT[g * kD + o0];
            short4 s4;
#pragma unroll
            for (int r = 0; r < 4; ++r)
                (&s4.x)[r] = f2bf((xv[nt][r] - mean) * rstd * (&w4.x)[r] + (&b4.x)[r]);
            *(short4*)&sA[g * AS + o0] = s4;
        }
    }
    __syncthreads();

    // ---- phase 2: MLP1 (4 mt: e range [w*64, w*64+64)) ----
    bf16x8 w2f[8];                            // W2 prefetch
    {
        bf16x8 afrA[2][2];
#pragma unroll
        for (int c = 0; c < 2; ++c)
#pragma unroll
            for (int nt = 0; nt < 2; ++nt)
                afrA[c][nt] = *(const bf16x8*)&sA[(nt * 16 + l16) * AS + c * 32 + quad * 8];

        f32x4 acc1[4][2];
#pragma unroll
        for (int mt = 0; mt < 4; ++mt)
#pragma unroll
            for (int nt = 0; nt < 2; ++nt) acc1[mt][nt] = (f32x4){0.f, 0.f, 0.f, 0.f};
#pragma unroll
        for (int mt = 0; mt < 4; ++mt)
#pragma unroll
            for (int c = 0; c < 2; ++c)
#pragma unroll
                for (int nt = 0; nt < 2; ++nt)
                    acc1[mt][nt] = __builtin_amdgcn_mfma_f32_16x16x32_bf16(w1f[mt * 2 + c], afrA[c][nt], acc1[mt][nt], 0, 0, 0);

#pragma unroll
        for (int c = 0; c < 8; ++c)
            w2f[c] = *(const bf16x8*)&W2h[(w * 16 + l16) * kE + c * 32 + quad * 8];

#pragma unroll
        for (int mt = 0; mt < 4; ++mt)
#pragma unroll
            for (int nt = 0; nt < 2; ++nt) {
                int g = nt * 16 + l16;
                int e0 = (w * 4 + mt) * 16 + quad * 4;
                const float4 b4 = *(const float4*)&b1T[g * kE + e0];
                short4 s4;
#pragma unroll
                for (int r = 0; r < 4; ++r)
                    (&s4.x)[r] = f2bf(tanh_fast(acc1[mt][nt][r] + (&b4.x)[r]));
                *(short4*)&sM[g * MS + e0] = s4;
            }
    }
    __syncthreads();

    // ---- phase 3: MLP2 (1 mt: o rows [w*16, w*16+16)) ----
    f32x4 acc2[2];
#pragma unroll
    for (int nt = 0; nt < 2; ++nt) acc2[nt] = (f32x4){0.f, 0.f, 0.f, 0.f};
#pragma unroll
    for (int c = 0; c < 8; ++c) {
        bf16x8 bq[2];
#pragma unroll
        for (int nt = 0; nt < 2; ++nt)
            bq[nt] = *(const bf16x8*)&sM[(nt * 16 + l16) * MS + c * 32 + quad * 8];
#pragma unroll
        for (int nt = 0; nt < 2; ++nt)
            acc2[nt] = __builtin_amdgcn_mfma_f32_16x16x32_bf16(w2f[c], bq[nt], acc2[nt], 0, 0, 0);
    }

    bf16x8 wqf[6];
    if constexpr (!LAST) {
        const unsigned short* Wp[3] = {Wqh, Wkh, Wvh};
#pragma unroll
        for (int m = 0; m < 3; ++m)
#pragma unroll
            for (int c = 0; c < 2; ++c)
                wqf[m * 2 + c] = *(const bf16x8*)&Wp[m][(w * 16 + l16) * kD + c * 32 + quad * 8];
    }

    // ---- phase 4: residual(reg) + mn -> XT; LN1(next) -> sA ----
    float yv[2][4];
    float s2 = 0.f, ss2 = 0.f;
    {
        float vv[2][4];
#pragma unroll
        for (int nt = 0; nt < 2; ++nt) {
            int g = nt * 16 + l16;
            const float4 b4 = *(const float4*)&b2T[g * kD + o0];
            const float4 g4 = *(const float4*)&gm2T[g * kD + o0];
#pragma unroll
            for (int r = 0; r < 4; ++r)
                vv[nt][r] = xv[nt][r] + (&g4.x)[r] * (acc2[nt][r] + (&b4.x)[r]);
        }
#pragma unroll
        for (int r = 0; r < 4; ++r) {
            float sq = vv[0][r] * vv[0][r] + vv[1][r] * vv[1][r];
#pragma unroll
            for (int off = 1; off < 16; off <<= 1) sq += __shfl_xor(sq, off, 64);
            float rn = 1.f / (sqrtf(sq) + 1e-6f);
#pragma unroll
            for (int nt = 0; nt < 2; ++nt) {
                float x = vv[nt][r] * rn;
                yv[nt][r] = x;
                s2 += x; ss2 = fmaf(x, x, ss2);
            }
        }
#pragma unroll
        for (int nt = 0; nt < 2; ++nt) {
            int g = nt * 16 + l16;
            float4 xo;
#pragma unroll
            for (int r = 0; r < 4; ++r) (&xo.x)[r] = yv[nt][r];
            *(float4*)&XT[tb + g * kD + o0] = xo;
        }
    }
    if constexpr (LAST) return;

#pragma unroll
    for (int off = 1; off < 64; off <<= 1) {
        s2 += __shfl_xor(s2, off, 64); ss2 += __shfl_xor(ss2, off, 64);
    }
    if (lane == 0) { sred[w] = s2; sred[4 + w] = ss2; }
    __syncthreads();
    {
        float st = sred[0] + sred[1] + sred[2] + sred[3];
        float sst = sred[4] + sred[5] + sred[6] + sred[7];
        float mean = st * (1.f / kDG);
        float var  = sst * (1.f / kDG) - mean * mean;
        float rstd = rsqrtf(var + 1e-5f);
#pragma unroll
        for (int nt = 0; nt < 2; ++nt) {
            int g = nt * 16 + l16;
            const float4 w4 = *(const float4*)&ln1wT[g * kD + o0];
            const float4 b4 = *(const float4*)&ln1bT[g * kD + o0];
            short4 s4;
#pragma unroll
            for (int r = 0; r < 4; ++r)
                (&s4.x)[r] = f2bf((yv[nt][r] - mean) * rstd * (&w4.x)[r] + (&b4.x)[r]);
            *(short4*)&sA[g * AS + o0] = s4;
        }
    }
    __syncthreads();

    // ---- phase 5: QKV(next) from sA with prefetched wqf ----
    {
        bf16x8 afrA[2][2];
#pragma unroll
        for (int c = 0; c < 2; ++c)
#pragma unroll
            for (int nt = 0; nt < 2; ++nt)
                afrA[c][nt] = *(const bf16x8*)&sA[(nt * 16 + l16) * AS + c * 32 + quad * 8];

        const float* Bp[3] = {bqT, bkT, bvT};
        unsigned short* Op[3] = {Q, K, V};
#pragma unroll
        for (int m = 0; m < 3; ++m) {
            f32x4 acc3[2];
#pragma unroll
            for (int nt = 0; nt < 2; ++nt) acc3[nt] = (f32x4){0.f, 0.f, 0.f, 0.f};
#pragma unroll
            for (int c = 0; c < 2; ++c)
#pragma unroll
                for (int nt = 0; nt < 2; ++nt)
                    acc3[nt] = __builtin_amdgcn_mfma_f32_16x16x32_bf16(wqf[m * 2 + c], afrA[c][nt], acc3[nt], 0, 0, 0);
            unsigned short* op = Op[m] + tb;
#pragma unroll
            for (int nt = 0; nt < 2; ++nt) {
                int g = nt * 16 + l16;
                const float4 b4 = *(const float4*)&Bp[m][g * kD + o0];
#pragma unroll
                for (int r = 0; r < 4; ++r)
                    op[(o0 + r) * kG + g] = (unsigned short)f2bf(acc3[nt][r] + (&b4.x)[r]);
            }
        }
    }
}

// ---------------- Q/K/V GEMM for layer 0 only ----------------
__global__ __launch_bounds__(256, 3) void gemm_qkv_kernel(
    const unsigned short* __restrict__ X,
    const unsigned short* __restrict__ Wqh, const unsigned short* __restrict__ Wkh,
    const unsigned short* __restrict__ Wvh,
    const float* __restrict__ bqT, const float* __restrict__ bkT, const float* __restrict__ bvT,
    unsigned short* __restrict__ Q, unsigned short* __restrict__ K, unsigned short* __restrict__ V) {
    constexpr int WS = 64 + 8;
    __shared__ short sW[3 * 64 * WS];

    const int tid = threadIdx.x, wave = tid >> 6, lane = tid & 63;
    const int l16 = lane & 15, quad = lane >> 4;
    const int tok = blockIdx.x * 4 + wave;

    const unsigned short* Wp[3] = {Wqh, Wkh, Wvh};
#pragma unroll
    for (int w = 0; w < 3; ++w)
        for (int j = tid * 8; j < 64 * 64; j += 2048) {
            int o = j >> 6, i = j & 63;
            *(bf16x8*)&sW[w * 64 * WS + o * WS + i] = *(const bf16x8*)(Wp[w] + j);
        }

    const unsigned short* xp = X + (size_t)tok * kDG;
    bf16x8 bfr[2][2];
#pragma unroll
    for (int c = 0; c < 2; ++c)
#pragma unroll
        for (int nt = 0; nt < 2; ++nt)
            bfr[c][nt] = *(const bf16x8*)&xp[(nt * 16 + l16) * kD + c * 32 + quad * 8];
    __syncthreads();

    f32x4 acc[3][4][2];
#pragma unroll
    for (int w = 0; w < 3; ++w)
#pragma unroll
        for (int mt = 0; mt < 4; ++mt)
#pragma unroll
            for (int nt = 0; nt < 2; ++nt) acc[w][mt][nt] = (f32x4){0.f, 0.f, 0.f, 0.f};

#pragma unroll
    for (int w = 0; w < 3; ++w)
#pragma unroll
        for (int mt = 0; mt < 4; ++mt)
#pragma unroll
            for (int c = 0; c < 2; ++c) {
                bf16x8 afr = *(const bf16x8*)&sW[w * 64 * WS + (mt * 16 + l16) * WS + c * 32 + quad * 8];
#pragma unroll
                for (int nt = 0; nt < 2; ++nt)
                    acc[w][mt][nt] = __builtin_amdgcn_mfma_f32_16x16x32_bf16(afr, bfr[c][nt], acc[w][mt][nt], 0, 0, 0);
            }

    unsigned short* Op[3] = {Q, K, V};
    const float* Bp[3] = {bqT, bkT, bvT};
#pragma unroll
    for (int w = 0; w < 3; ++w) {
        unsigned short* op = Op[w] + (size_t)tok * kDG;
#pragma unroll
        for (int mt = 0; mt < 4; ++mt)
#pragma unroll
            for (int nt = 0; nt < 2; ++nt) {
                int g = nt * 16 + l16;
                int o0 = mt * 16 + quad * 4;
                const float4 b4 = *(const float4*)&Bp[w][g * kD + o0];
#pragma unroll
                for (int r = 0; r < 4; ++r)
                    op[(o0 + r) * kG + g] = (unsigned short)f2bf(acc[w][mt][nt][r] + (&b4.x)[r]);
            }
    }
}

// ---------------- MFMA attention v6: direct-L2 Q/K operands ----------------
// 32-row Q tiles, 2 waves/block (R8 geometry), but Q and K MFMA fragments are
// 16B-contiguous rows of L2-resident tensors -> load them DIRECTLY from
// global. Deletes Q-stage, K-stage and all 7 K-loop barriers; the QK phase is
// a fully-unrolled load+MFMA stream the compiler can pipeline freely (at 1
// wave/SIMD the VGPR budget is ~512, so deep load-ahead is available).
// V keeps the proven double-buffered gather-transpose (needs the transpose).
constexpr int QSTR = 264;
constexpr int VSTR = 40;

__global__ __launch_bounds__(128) void attn_mfma_kernel(const unsigned short* __restrict__ Q,
                                                        const unsigned short* __restrict__ K,
                                                        const unsigned short* __restrict__ V,
                                                        unsigned short* __restrict__ O) {
    __shared__ short sP[32 * QSTR];          // 16.9 KB: P tile (same-wave use only)
    __shared__ short sKV[2][256 * VSTR];     // 41 KB: V^T double buffer

    const int qt = blockIdx.x, h = blockIdx.y, b = blockIdx.z;
    const int tid = threadIdx.x;
    const int wave = tid >> 6, lane = tid & 63;
    const int l16 = lane & 15, quad = lane >> 4;

    const size_t bh = (size_t)b * kS * kDG + (size_t)h * kHD;

    // Q fragments: direct from global (16B contiguous per lane, L2-hot)
    bf16x8 afrag[8];
    {
        const unsigned short* qp = Q + bh + (size_t)(qt * 32 + wave * 16 + l16) * kDG;
#pragma unroll
        for (int c = 0; c < 8; ++c)
            afrag[c] = *(const bf16x8*)(qp + c * 32 + quad * 8);
    }

    // QK^T: direct K fragment loads, zero barriers, fully unrolled
    f32x4 acc[16];
#pragma unroll
    for (int i = 0; i < 16; ++i) acc[i] = (f32x4){0.f, 0.f, 0.f, 0.f};

#pragma unroll
    for (int kt = 0; kt < 8; ++kt)
#pragma unroll
        for (int nt = 0; nt < 2; ++nt) {
            const unsigned short* kp = K + bh + (size_t)(kt * 32 + nt * 16 + l16) * kDG;
            f32x4 a = acc[kt * 2 + nt];
#pragma unroll
            for (int c = 0; c < 8; ++c) {
                bf16x8 bfrag = *(const bf16x8*)(kp + c * 32 + quad * 8);
                a = __builtin_amdgcn_mfma_f32_16x16x32_bf16(afrag[c], bfrag, a, 0, 0, 0);
            }
            acc[kt * 2 + nt] = a;
        }

    // softmax over 256 keys (rows = quad*4 + r)
    float inv[4];
#pragma unroll
    for (int r = 0; r < 4; ++r) {
        float m = -1e30f;
#pragma unroll
        for (int t = 0; t < 16; ++t) m = fmaxf(m, acc[t][r]);
#pragma unroll
        for (int off = 1; off < 16; off <<= 1) m = fmaxf(m, __shfl_xor(m, off, 16));
        float s = 0.f;
#pragma unroll
        for (int t = 0; t < 16; ++t) {
            float p = __expf((acc[t][r] - m) * 0.0625f);
            acc[t][r] = p; s += p;
        }
#pragma unroll
        for (int off = 1; off < 16; off <<= 1) s += __shfl_xor(s, off, 16);
        inv[r] = 1.f / s;
    }

    // P (bf16) into sP — each wave writes/reads only its own 16 rows
#pragma unroll
    for (int t = 0; t < 16; ++t)
#pragma unroll
        for (int r = 0; r < 4; ++r)
            sP[(wave * 16 + quad * 4 + r) * QSTR + t * 16 + l16] = f2bf(acc[t][r]);

    // V^T tile 0 into buf 0 (128-thr gather-transpose)
    {
        const int db = tid & 63, kh = tid >> 6;
        short4 vr[16];
#pragma unroll
        for (int r = 0; r < 16; ++r)
            vr[r] = *(const short4*)(V + bh + (size_t)(kh * 16 + r) * kDG + db * 4);
#pragma unroll
        for (int i = 0; i < 4; ++i)
#pragma unroll
            for (int gq = 0; gq < 4; ++gq) {
                short4 p = make_short4((&vr[gq * 4 + 0].x)[i], (&vr[gq * 4 + 1].x)[i],
                                       (&vr[gq * 4 + 2].x)[i], (&vr[gq * 4 + 3].x)[i]);
                *(short4*)&sKV[0][(db * 4 + i) * VSTR + kh * 16 + gq * 4] = p;
            }
    }
    __syncthreads();

    f32x4 oacc[16];
#pragma unroll
    for (int i = 0; i < 16; ++i) oacc[i] = (f32x4){0.f, 0.f, 0.f, 0.f};

    for (int vt = 0; vt < 8; ++vt) {
        short4 vpre[16];
        if (vt < 7) {
            const int db = tid & 63, kh = tid >> 6;
#pragma unroll
            for (int r = 0; r < 16; ++r)
                vpre[r] = *(const short4*)(V + bh + (size_t)((vt + 1) * 32 + kh * 16 + r) * kDG + db * 4);
        }
        const short* vb = sKV[vt & 1];
        bf16x8 pfrag = *(const bf16x8*)&sP[(wave * 16 + l16) * QSTR + vt * 32 + quad * 8];
#pragma unroll
        for (int dt = 0; dt < 16; ++dt) {
            bf16x8 vfrag = *(const bf16x8*)&vb[(dt * 16 + l16) * VSTR + quad * 8];
            oacc[dt] = __builtin_amdgcn_mfma_f32_16x16x32_bf16(pfrag, vfrag, oacc[dt], 0, 0, 0);
        }
        if (vt < 7) {
            const int db = tid & 63, kh = tid >> 6;
            short* nb = sKV[(vt + 1) & 1];
#pragma unroll
            for (int i = 0; i < 4; ++i)
#pragma unroll
                for (int gq = 0; gq < 4; ++gq) {
                    short4 p = make_short4((&vpre[gq * 4 + 0].x)[i], (&vpre[gq * 4 + 1].x)[i],
                                           (&vpre[gq * 4 + 2].x)[i], (&vpre[gq * 4 + 3].x)[i]);
                    *(short4*)&nb[(db * 4 + i) * VSTR + kh * 16 + gq * 4] = p;
                }
            __syncthreads();
        }
    }

    // O write: bf16 T-layout [tok][g*64 + h*8 + dl]
    {
        const size_t ob = (size_t)(b * kS + qt * 32 + wave * 16 + quad * 4) * kDG + h * 8;
#pragma unroll
        for (int gg = 0; gg < 2; ++gg) {
            int g = gg * 16 + l16;
#pragma unroll
            for (int r = 0; r < 4; ++r) {
                bf16x8 pk;
#pragma unroll
                for (int k = 0; k < 8; ++k)
                    pk[k] = f2bf(oacc[k * 2 + gg][r] * inv[r]);
                *(bf16x8*)&O[ob + (size_t)r * kDG + g * kD] = pk;
            }
        }
    }
}

// ---------------- in-thread geometric product with compile-time signs -------
constexpr int pc_ce(unsigned v) { int c = 0; while (v) { c += v & 1; v >>= 1; } return c; }
constexpr unsigned gp_mask_ce(int a) {
    unsigned m = 0;
    for (int c = 0; c < 32; ++c) {
        int b = a ^ c;
        int s = (a & b) >> 4;
        for (int t = a >> 1; t; t >>= 1) s += pc_ce(t & b);
        if (s & 1) m |= (1u << c);
    }
    return m;
}

template<int A>
__device__ __forceinline__ void gp_term(const float* x, const float* y, float* acc) {
    constexpr unsigned m = gp_mask_ce(A);
    const float xa = x[A], nxa = -xa;
#pragma unroll
    for (int c = 0; c < 32; ++c)
        acc[c] = fmaf(((m >> c) & 1u) ? nxa : xa, y[A ^ c], acc[c]);
}

__device__ __forceinline__ void gp_mn_t(const float* x, const float* y, float* out) {
    float acc[32];
#pragma unroll
    for (int c = 0; c < 32; ++c) acc[c] = 0.f;
    gp_term<0>(x, y, acc);  gp_term<1>(x, y, acc);  gp_term<2>(x, y, acc);  gp_term<3>(x, y, acc);
    gp_term<4>(x, y, acc);  gp_term<5>(x, y, acc);  gp_term<6>(x, y, acc);  gp_term<7>(x, y, acc);
    gp_term<8>(x, y, acc);  gp_term<9>(x, y, acc);  gp_term<10>(x, y, acc); gp_term<11>(x, y, acc);
    gp_term<12>(x, y, acc); gp_term<13>(x, y, acc); gp_term<14>(x, y, acc); gp_term<15>(x, y, acc);
    gp_term<16>(x, y, acc); gp_term<17>(x, y, acc); gp_term<18>(x, y, acc); gp_term<19>(x, y, acc);
    gp_term<20>(x, y, acc); gp_term<21>(x, y, acc); gp_term<22>(x, y, acc); gp_term<23>(x, y, acc);
    gp_term<24>(x, y, acc); gp_term<25>(x, y, acc); gp_term<26>(x, y, acc); gp_term<27>(x, y, acc);
    gp_term<28>(x, y, acc); gp_term<29>(x, y, acc); gp_term<30>(x, y, acc); gp_term<31>(x, y, acc);
    float ss = 0.f;
#pragma unroll
    for (int c = 0; c < 32; ++c) ss = fmaf(acc[c], acc[c], ss);
    float r = 1.f / (sqrtf(ss) + 1e-6f);
#pragma unroll
    for (int c = 0; c < 32; ++c) out[c] = acc[c] * r;
}

__device__ __forceinline__ void leaf_load(const float* base, float* v) {
#pragma unroll
    for (int i = 0; i < 8; ++i) {
        const float4 f = *(const float4*)(base + i * 4);
        v[i * 4 + 0] = 0.5f * f.x; v[i * 4 + 1] = 0.5f * f.y;
        v[i * 4 + 2] = 0.5f * f.z; v[i * 4 + 3] = 0.5f * f.w;
    }
    v[0] += 1.f;
    float ss = 0.f;
#pragma unroll
    for (int c = 0; c < 32; ++c) ss = fmaf(v[c], v[c], ss);
    float r = 1.f / (sqrtf(ss) + 1e-6f);
#pragma unroll
    for (int c = 0; c < 32; ++c) v[c] *= r;
}

// ---------------- scan: 1 wave per sequence, 1 block per wave ---------------
__global__ __launch_bounds__(64) void scanreg_kernel(const float* __restrict__ DT,
                                                     float* __restrict__ pooled) {
    const int lane = threadIdx.x & 63;
    const int seq = blockIdx.x;
    const float* base = DT + ((size_t)seq * kS + lane * 4) * kG;

    float R[32], Y[32], P[32], Xa[32], Yb[32];

    leaf_load(base, R);
    for (int j = 1; j < 4; ++j) {
        leaf_load(base + j * kG, Y);
        gp_mn_t(Y, R, R);
    }

    for (int step = 1; step < 64; step <<= 1) {
        const bool up = lane & step;
#pragma unroll
        for (int c = 0; c < 32; ++c) P[c] = __shfl_xor(R[c], step, 64);
#pragma unroll
        for (int c = 0; c < 32; ++c) {
            Xa[c] = up ? R[c] : P[c];
            Yb[c] = up ? P[c] : R[c];
        }
        gp_mn_t(Xa, Yb, R);
    }

    if (lane == 0) {
        float* op = pooled + (size_t)seq * kG;
#pragma unroll
        for (int i = 0; i < 8; ++i)
            *(float4*)(op + i * 4) = make_float4(R[i * 4], R[i * 4 + 1], R[i * 4 + 2], R[i * 4 + 3]);
    }
}

// ---------------- classifier ----------------
__global__ __launch_bounds__(256) void cls2_kernel(const float* __restrict__ P,
                                                   const float* __restrict__ Wc,
                                                   const float* __restrict__ bc,
                                                   float* __restrict__ out) {
    __shared__ float sp[kB * kDG];
    const int tid = threadIdx.x, wave = tid >> 6, lane = tid & 63;
    for (int j = tid * 4; j < kB * kDG; j += 1024)
        *(float4*)&sp[j] = *(const float4*)(P + j);
    __syncthreads();

    const int c = blockIdx.x * 4 + wave;
    const float* w = Wc + (size_t)c * kDG;
    float acc[kB];
#pragma unroll
    for (int b = 0; b < kB; ++b) acc[b] = 0.f;
#pragma unroll
    for (int cc = 0; cc < 8; ++cc) {
        const float4 w4 = *(const float4*)(w + cc * 256 + lane * 4);
#pragma unroll
        for (int b = 0; b < kB; ++b) {
            const float4 p4 = *(const float4*)&sp[b * kDG + cc * 256 + lane * 4];
            acc[b] += w4.x * p4.x + w4.y * p4.y + w4.z * p4.z + w4.w * p4.w;
        }
    }
#pragma unroll
    for (int b = 0; b < kB; ++b)
#pragma unroll
        for (int off = 32; off > 0; off >>= 1) acc[b] += __shfl_xor(acc[b], off, 64);
    if (lane == 0) {
        float bias = bc[c];
#pragma unroll
        for (int b = 0; b < kB; ++b) out[b * kNC + c] = acc[b] + bias;
    }
}

extern "C" void kernel_launch(void* const* d_in, const int* in_sizes, int n_in,
                              void* d_out, int out_size, void* d_ws, size_t ws_size,
                              hipStream_t stream) {
    const float* x_in = (const float*)d_in[0];
    const float* Wq   = (const float*)d_in[1];
    const float* bq   = (const float*)d_in[2];
    const float* Wk   = (const float*)d_in[3];
    const float* bk   = (const float*)d_in[4];
    const float* Wv   = (const float*)d_in[5];
    const float* bv   = (const float*)d_in[6];
    const float* Wo   = (const float*)d_in[7];
    const float* bo   = (const float*)d_in[8];
    const float* ln1w = (const float*)d_in[9];
    const float* ln1b = (const float*)d_in[10];
    const float* ln2w = (const float*)d_in[11];
    const float* ln2b = (const float*)d_in[12];
    const float* gm1  = (const float*)d_in[13];
    const float* gm2  = (const float*)d_in[14];
    const float* W1   = (const float*)d_in[15];
    const float* b1   = (const float*)d_in[16];
    const float* W2   = (const float*)d_in[17];
    const float* b2   = (const float*)d_in[18];
    const float* Wr   = (const float*)d_in[19];
    const float* br   = (const float*)d_in[20];
    const float* Wc   = (const float*)d_in[21];
    const float* bc   = (const float*)d_in[22];

    const size_t NEL = (size_t)kT * kDG;
    float* F  = (float*)d_ws;
    float* XT = F;                                   // region 0: fp32 residual, T-layout
    unsigned short* Abf = (unsigned short*)(F + NEL);// region 1: attn in (A) / attn out (O)
    unsigned short* Qh = (unsigned short*)(F + 2 * NEL);
    unsigned short* Kh = (unsigned short*)(F + 3 * NEL);
    unsigned short* Vh = (unsigned short*)(F + 4 * NEL);
    unsigned short* Wb = (unsigned short*)(F + 5 * NEL);   // bf16 weights (384 KB)
    float* PT = F + 3 * NEL + NEL / 2;               // T-params (480 KB, gap after Kh)
    float* pooled = F + 2 * NEL;
    float* DT = F + NEL;

    cvtw_kernel<<<192, 256, 0, stream>>>(Wq, Wk, Wv, Wo, W1, W2, Wb);
    prep_tr_kernel<<<48, 256, 0, stream>>>(bq, bk, bv, bo, b2, gm1, gm2,
                                           ln2w, ln2b, ln1w, ln1b, b1, PT);
    unsigned short* Wqh = Wb;
    unsigned short* Wkh = Wb + 16384;
    unsigned short* Wvh = Wb + 32768;
    unsigned short* Woh = Wb + 49152;
    unsigned short* W1h = Wb + 65536;
    unsigned short* W2h = Wb + 131072;

    auto bqT   = [&](int l) { return PT + 0     + l * 2048; };
    auto bkT   = [&](int l) { return PT + 8192  + l * 2048; };
    auto bvT   = [&](int l) { return PT + 16384 + l * 2048; };
    auto boT   = [&](int l) { return PT + 24576 + l * 2048; };
    auto b2T   = [&](int l) { return PT + 32768 + l * 2048; };
    auto gm1T  = [&](int l) { return PT + 40960 + l * 2048; };
    auto gm2T  = [&](int l) { return PT + 49152 + l * 2048; };
    auto ln2wT = [&](int l) { return PT + 57344 + l * 2048; };
    auto ln2bT = [&](int l) { return PT + 65536 + l * 2048; };
    auto ln1wT = [&](int l) { return PT + 73728 + l * 2048; };
    auto ln1bT = [&](int l) { return PT + 81920 + l * 2048; };
    auto b1T   = [&](int l) { return PT + 90112 + l * 8192; };

    ln_kernel<<<kT, 256, 0, stream>>>(x_in, ln1w, ln1b, Abf, XT);
    gemm_qkv_kernel<<<kT / 4, 256, 0, stream>>>(Abf,
        Wqh, Wkh, Wvh, bqT(0), bkT(0), bvT(0), Qh, Kh, Vh);

    for (int l = 0; l < 4; l++) {
        attn_mfma_kernel<<<dim3(8, kNH, kB), 128, 0, stream>>>(Qh, Kh, Vh, Abf);
        if (l < 3)
            mega_kernel<false><<<kT, 256, 0, stream>>>(Abf,
                Woh + l * 4096, boT(l), gm1T(l), ln2wT(l), ln2bT(l),
                W1h + l * 16384, b1T(l), W2h + l * 16384, b2T(l), gm2T(l),
                ln1wT(l + 1), ln1bT(l + 1), XT,
                Wqh + (l + 1) * 4096, Wkh + (l + 1) * 4096, Wvh + (l + 1) * 4096,
                bqT(l + 1), bkT(l + 1), bvT(l + 1), Qh, Kh, Vh);
        else
            mega_kernel<true><<<kT, 256, 0, stream>>>(Abf,
                Woh + l * 4096, boT(l), gm1T(l), ln2wT(l), ln2bT(l),
                W1h + l * 16384, b1T(l), W2h + l * 16384, b2T(l), gm2T(l),
                nullptr, nullptr, XT,
                nullptr, nullptr, nullptr, nullptr, nullptr, nullptr,
                nullptr, nullptr, nullptr);
    }

    vlinT_kernel<<<kT, 256, 0, stream>>>(XT, Wr, br, DT);
    scanreg_kernel<<<kB * kD, 64, 0, stream>>>(DT, pooled);
    cls2_kernel<<<kNC / 4, 256, 0, stream>>>(pooled, Wc, bc, (float*)d_out);
}

// Round 11
// 510.210 us; speedup vs baseline: 1.0512x; 1.0462x over previous
//
#include <hip/hip_runtime.h>
#include <hip/hip_bf16.h>

// Problem constants (B=8, S=256, D=64, G=32, E=256, L=4, NH=8, DH=8)
constexpr int kB  = 8;
constexpr int kS  = 256;
constexpr int kD  = 64;
constexpr int kG  = 32;
constexpr int kE  = 256;
constexpr int kNH = 8;
constexpr int kHD = 256;              // DH*G = 8*32
constexpr int kDG = kD * kG;          // 2048
constexpr int kT  = kB * kS;          // 2048 tokens
constexpr int kNC = 1000;

using bf16x8 = __attribute__((ext_vector_type(8))) short;
using f32x4  = __attribute__((ext_vector_type(4))) float;

__device__ __forceinline__ short f2bf(float f) {
    unsigned u = __float_as_uint(f);
    unsigned r = (u + 0x7FFFu + ((u >> 16) & 1u)) >> 16;   // RNE
    return (short)r;
}

__device__ __forceinline__ float tanh_fast(float x) {
    float a = fabsf(x);
    float e = __expf(-2.f * a);
    float d = 1.f + e;
    float r = __builtin_amdgcn_rcpf(d);
    r = r * (2.f - d * r);
    float t = (1.f - e) * r;
    return copysignf(t, x);
}

// ---------------- one-time weight fp32->bf16 conversion ----------------
__global__ __launch_bounds__(256) void cvtw_kernel(
    const float* __restrict__ Wq, const float* __restrict__ Wk,
    const float* __restrict__ Wv, const float* __restrict__ Wo,
    const float* __restrict__ W1, const float* __restrict__ W2,
    unsigned short* __restrict__ dst) {
    int idx = (blockIdx.x * 256 + threadIdx.x) * 4;
    const float* src; int off;
    if      (idx <  16384) { src = Wq; off = 0; }
    else if (idx <  32768) { src = Wk; off = 16384; }
    else if (idx <  49152) { src = Wv; off = 32768; }
    else if (idx <  65536) { src = Wo; off = 49152; }
    else if (idx < 131072) { src = W1; off = 65536; }
    else                   { src = W2; off = 131072; }
    const float4 v = *(const float4*)(src + (idx - off));
    *(short4*)&dst[idx] = make_short4(f2bf(v.x), f2bf(v.y), f2bf(v.z), f2bf(v.w));
}

// ---------------- one-time param transpose [R][32] -> [32][R] ---------------
__global__ __launch_bounds__(256) void prep_tr_kernel(
    const float* __restrict__ bq, const float* __restrict__ bk,
    const float* __restrict__ bv, const float* __restrict__ bo,
    const float* __restrict__ b2, const float* __restrict__ gm1,
    const float* __restrict__ gm2, const float* __restrict__ ln2w,
    const float* __restrict__ ln2b, const float* __restrict__ ln1w,
    const float* __restrict__ ln1b, const float* __restrict__ b1,
    float* __restrict__ dst) {
    __shared__ float lt[32 * 257];
    const int a = blockIdx.x >> 2, l = blockIdx.x & 3;
    const float* srcs[12] = {bq, bk, bv, bo, b2, gm1, gm2, ln2w, ln2b, ln1w, ln1b, b1};
    const int R  = (a == 11) ? 256 : 64;
    const int sh = (a == 11) ? 8 : 6;
    const float* src = srcs[a] + (size_t)l * R * 32;
    float* out = dst + a * 8192 + l * R * 32;
    const int tid = threadIdx.x;
    for (int j = tid; j < R * 32; j += 256) lt[(j & 31) * (R + 1) + (j >> 5)] = src[j];
    __syncthreads();
    for (int k = tid; k < R * 32; k += 256) {
        int g = k >> sh, r = k & (R - 1);
        out[k] = lt[g * (R + 1) + r];
    }
}

// ---------------- LN of x_in -> bf16 A (T-layout) + fp32 XT (= x_in^T) -----
__global__ __launch_bounds__(256) void ln_kernel(const float* __restrict__ Xin,
                                                 const float* __restrict__ w,
                                                 const float* __restrict__ b,
                                                 unsigned short* __restrict__ A,
                                                 float* __restrict__ XT) {
    int t = blockIdx.x, tid = threadIdx.x;
    const float* xp = Xin + (size_t)t * kDG;
    __shared__ float r1[256], r2[256];
    __shared__ short st[32 * 72];
    __shared__ float xf[32 * 68];
    float v[8], s = 0.f, ss = 0.f;
#pragma unroll
    for (int j = 0; j < 8; j++) {
        float x = xp[tid + j * 256];
        v[j] = x; s += x; ss += x * x;
        int jj = tid + j * 256;
        xf[(jj & 31) * 68 + (jj >> 5)] = x;
    }
    r1[tid] = s; r2[tid] = ss; __syncthreads();
    for (int o = 128; o > 0; o >>= 1) {
        if (tid < o) { r1[tid] += r1[tid + o]; r2[tid] += r2[tid + o]; }
        __syncthreads();
    }
    float mean = r1[0] * (1.f / kDG);
    float var  = r2[0] * (1.f / kDG) - mean * mean;
    float rstd = rsqrtf(var + 1e-5f);
#pragma unroll
    for (int j = 0; j < 8; j++) {
        int jj = tid + j * 256;                    // jj = d*32 + g
        float val = (v[j] - mean) * rstd * w[jj] + b[jj];
        st[(jj & 31) * 72 + (jj >> 5)] = f2bf(val);
    }
    __syncthreads();
    bf16x8 ov = *(const bf16x8*)&st[(tid >> 3) * 72 + (tid & 7) * 8];
    *(bf16x8*)&A[(size_t)t * kDG + tid * 8] = ov;
    const int row = tid >> 3, col = (tid & 7) * 8;
    float* xo = XT + (size_t)t * kDG + tid * 8;
    *(float4*)(xo + 0) = *(const float4*)&xf[row * 68 + col + 0];
    *(float4*)(xo + 4) = *(const float4*)&xf[row * 68 + col + 4];
}

// ---------------- scalar fp32 versor_linear (X in T-layout) -----------------
__global__ __launch_bounds__(256) void vlinT_kernel(const float* __restrict__ XT,
                                                    const float* __restrict__ W,
                                                    const float* __restrict__ bias,
                                                    float* __restrict__ OutT) {
    __shared__ float sx[32 * 65];
    __shared__ float sw[kD * kD];
    int t = blockIdx.x, tid = threadIdx.x;
    const float* xp = XT + (size_t)t * kDG;
    for (int j = tid; j < kDG; j += 256) sx[(j >> 6) * 65 + (j & 63)] = xp[j];
    for (int j = tid; j < kD * kD; j += 256) sw[j] = W[j];
    __syncthreads();
    int g = tid & 31, ob = tid >> 5;
    int b = t >> 8, s = t & 255;
    float* op = OutT + ((size_t)b * kD * kS + s) * kG;
    for (int o = ob; o < kD; o += 8) {
        float acc = bias[o * kG + g];
        const float* wr = sw + o * kD;
#pragma unroll
        for (int i = 0; i < kD; i++) acc += wr[i] * sx[g * 65 + i];
        op[(size_t)o * kS * kG + g] = acc;
    }
}

// ---------------- MEGA v4: R8 structure + pre-barrier param prefetch -------
// Post-barrier L2 loads (ln2w/b after B1, ln1w/b after B4, q/k/v biases after
// B5) sit in short regions with no latency cover; __syncthreads blocks
// compiler hoisting. Issue them into registers BEFORE the barrier instead
// (they depend on nothing). +~40 VGPR peak; occupancy is LDS-limited -> free.
template<bool LAST>
__global__ __launch_bounds__(256, 2) void mega_kernel(
    const unsigned short* __restrict__ O,     // attn out bf16 T [tok][g][d]
    const unsigned short* __restrict__ Woh, const float* __restrict__ boT,
    const float* __restrict__ gm1T,
    const float* __restrict__ ln2wT, const float* __restrict__ ln2bT,
    const unsigned short* __restrict__ W1h, const float* __restrict__ b1T,
    const unsigned short* __restrict__ W2h, const float* __restrict__ b2T,
    const float* __restrict__ gm2T,
    const float* __restrict__ ln1wT, const float* __restrict__ ln1bT,
    float* __restrict__ XT,
    const unsigned short* __restrict__ Wqh, const unsigned short* __restrict__ Wkh,
    const unsigned short* __restrict__ Wvh,
    const float* __restrict__ bqT, const float* __restrict__ bkT,
    const float* __restrict__ bvT,
    unsigned short* __restrict__ Q, unsigned short* __restrict__ K,
    unsigned short* __restrict__ V) {
    constexpr int AS = 72;                    // A-tile stride (shorts)
    constexpr int MS = 264;                   // M-tile stride
    __shared__ short sA[32 * AS];             // 4.6 KB  [g][o]
    __shared__ short sM[32 * MS];             // 16.9 KB [g][e]
    __shared__ float sred[8];

    const int tid = threadIdx.x;
    const int w = tid >> 6, lane = tid & 63;
    const int l16 = lane & 15, quad = lane >> 4;
    const int tok = blockIdx.x;
    const size_t tb = (size_t)tok * kDG;
    const int o0 = w * 16 + quad * 4;         // this wave's o window (64-row mats)

    // ---- phase 0: Wo GEMM (1 mt: o rows [w*16, w*16+16)) ----
    float xv[2][4];                           // residual X, carried in regs
    bf16x8 w1f[8];                            // W1 prefetch (4 mt x 2 c)
    {
        const unsigned short* xp = O + tb;
        bf16x8 bfr[2][2];
#pragma unroll
        for (int c = 0; c < 2; ++c)
#pragma unroll
            for (int nt = 0; nt < 2; ++nt)
                bfr[c][nt] = *(const bf16x8*)&xp[(nt * 16 + l16) * kD + c * 32 + quad * 8];

        f32x4 accW[2];
#pragma unroll
        for (int nt = 0; nt < 2; ++nt) accW[nt] = (f32x4){0.f, 0.f, 0.f, 0.f};
#pragma unroll
        for (int c = 0; c < 2; ++c) {
            bf16x8 afr = *(const bf16x8*)&Woh[(w * 16 + l16) * kD + c * 32 + quad * 8];
#pragma unroll
            for (int nt = 0; nt < 2; ++nt)
                accW[nt] = __builtin_amdgcn_mfma_f32_16x16x32_bf16(afr, bfr[c][nt], accW[nt], 0, 0, 0);
        }

#pragma unroll
        for (int mt = 0; mt < 4; ++mt)
#pragma unroll
            for (int c = 0; c < 2; ++c)
                w1f[mt * 2 + c] = *(const bf16x8*)&W1h[((w * 4 + mt) * 16 + l16) * kD + c * 32 + quad * 8];

        // prefetch post-B1 params into regs (latency hides under reduce chain)
        float4 lw2[2], lb2[2];
#pragma unroll
        for (int nt = 0; nt < 2; ++nt) {
            int g = nt * 16 + l16;
            lw2[nt] = *(const float4*)&ln2wT[g * kD + o0];
            lb2[nt] = *(const float4*)&ln2bT[g * kD + o0];
        }

        // ---- phase 1: residual + mn (X in regs), LN2 -> sA ----
        float s = 0.f, ss = 0.f;
        float vv[2][4];
#pragma unroll
        for (int nt = 0; nt < 2; ++nt) {
            int g = nt * 16 + l16;
            const float4 b4 = *(const float4*)&boT[g * kD + o0];
            const float4 g4 = *(const float4*)&gm1T[g * kD + o0];
            const float4 xi = *(const float4*)&XT[tb + g * kD + o0];
#pragma unroll
            for (int r = 0; r < 4; ++r)
                vv[nt][r] = (&xi.x)[r] + (&g4.x)[r] * (accW[nt][r] + (&b4.x)[r]);
        }
#pragma unroll
        for (int r = 0; r < 4; ++r) {
            float sq = vv[0][r] * vv[0][r] + vv[1][r] * vv[1][r];
#pragma unroll
            for (int off = 1; off < 16; off <<= 1) sq += __shfl_xor(sq, off, 64);
            float rn = 1.f / (sqrtf(sq) + 1e-6f);
#pragma unroll
            for (int nt = 0; nt < 2; ++nt) {
                float x = vv[nt][r] * rn;
                xv[nt][r] = x;
                s += x; ss = fmaf(x, x, ss);
            }
        }
#pragma unroll
        for (int off = 1; off < 64; off <<= 1) {
            s += __shfl_xor(s, off, 64); ss += __shfl_xor(ss, off, 64);
        }
        if (lane == 0) { sred[w] = s; sred[4 + w] = ss; }
        __syncthreads();                      // B1
        float st = sred[0] + sred[1] + sred[2] + sred[3];
        float sst = sred[4] + sred[5] + sred[6] + sred[7];
        float mean = st * (1.f / kDG);
        float var  = sst * (1.f / kDG) - mean * mean;
        float rstd = rsqrtf(var + 1e-5f);
#pragma unroll
        for (int nt = 0; nt < 2; ++nt) {
            int g = nt * 16 + l16;
            short4 s4;
#pragma unroll
            for (int r = 0; r < 4; ++r)
                (&s4.x)[r] = f2bf((xv[nt][r] - mean) * rstd * (&lw2[nt].x)[r] + (&lb2[nt].x)[r]);
            *(short4*)&sA[g * AS + o0] = s4;
        }
    }
    __syncthreads();                          // B2

    // ---- phase 2: MLP1 (4 mt: e range [w*64, w*64+64)) ----
    bf16x8 w2f[8];                            // W2 prefetch
    {
        bf16x8 afrA[2][2];
#pragma unroll
        for (int c = 0; c < 2; ++c)
#pragma unroll
            for (int nt = 0; nt < 2; ++nt)
                afrA[c][nt] = *(const bf16x8*)&sA[(nt * 16 + l16) * AS + c * 32 + quad * 8];

        f32x4 acc1[4][2];
#pragma unroll
        for (int mt = 0; mt < 4; ++mt)
#pragma unroll
            for (int nt = 0; nt < 2; ++nt) acc1[mt][nt] = (f32x4){0.f, 0.f, 0.f, 0.f};
#pragma unroll
        for (int mt = 0; mt < 4; ++mt)
#pragma unroll
            for (int c = 0; c < 2; ++c)
#pragma unroll
                for (int nt = 0; nt < 2; ++nt)
                    acc1[mt][nt] = __builtin_amdgcn_mfma_f32_16x16x32_bf16(w1f[mt * 2 + c], afrA[c][nt], acc1[mt][nt], 0, 0, 0);

#pragma unroll
        for (int c = 0; c < 8; ++c)
            w2f[c] = *(const bf16x8*)&W2h[(w * 16 + l16) * kE + c * 32 + quad * 8];

#pragma unroll
        for (int mt = 0; mt < 4; ++mt)
#pragma unroll
            for (int nt = 0; nt < 2; ++nt) {
                int g = nt * 16 + l16;
                int e0 = (w * 4 + mt) * 16 + quad * 4;
                const float4 b4 = *(const float4*)&b1T[g * kE + e0];
                short4 s4;
#pragma unroll
                for (int r = 0; r < 4; ++r)
                    (&s4.x)[r] = f2bf(tanh_fast(acc1[mt][nt][r] + (&b4.x)[r]));
                *(short4*)&sM[g * MS + e0] = s4;
            }
    }
    __syncthreads();                          // B3

    // ---- phase 3: MLP2 (1 mt: o rows [w*16, w*16+16)) ----
    f32x4 acc2[2];
#pragma unroll
    for (int nt = 0; nt < 2; ++nt) acc2[nt] = (f32x4){0.f, 0.f, 0.f, 0.f};
#pragma unroll
    for (int c = 0; c < 8; ++c) {
        bf16x8 bq[2];
#pragma unroll
        for (int nt = 0; nt < 2; ++nt)
            bq[nt] = *(const bf16x8*)&sM[(nt * 16 + l16) * MS + c * 32 + quad * 8];
#pragma unroll
        for (int nt = 0; nt < 2; ++nt)
            acc2[nt] = __builtin_amdgcn_mfma_f32_16x16x32_bf16(w2f[c], bq[nt], acc2[nt], 0, 0, 0);
    }

    // prefetch next-layer QKV weights + post-B4/B5 params
    bf16x8 wqf[6];
    float4 lw1[2], lb1[2], pbq[2], pbk[2], pbv[2];
    if constexpr (!LAST) {
        const unsigned short* Wp[3] = {Wqh, Wkh, Wvh};
#pragma unroll
        for (int m = 0; m < 3; ++m)
#pragma unroll
            for (int c = 0; c < 2; ++c)
                wqf[m * 2 + c] = *(const bf16x8*)&Wp[m][(w * 16 + l16) * kD + c * 32 + quad * 8];
#pragma unroll
        for (int nt = 0; nt < 2; ++nt) {
            int g = nt * 16 + l16;
            lw1[nt] = *(const float4*)&ln1wT[g * kD + o0];
            lb1[nt] = *(const float4*)&ln1bT[g * kD + o0];
            pbq[nt] = *(const float4*)&bqT[g * kD + o0];
            pbk[nt] = *(const float4*)&bkT[g * kD + o0];
            pbv[nt] = *(const float4*)&bvT[g * kD + o0];
        }
    }

    // ---- phase 4: residual(reg) + mn -> XT; LN1(next) -> sA ----
    float yv[2][4];
    float s2 = 0.f, ss2 = 0.f;
    {
        float vv[2][4];
#pragma unroll
        for (int nt = 0; nt < 2; ++nt) {
            int g = nt * 16 + l16;
            const float4 b4 = *(const float4*)&b2T[g * kD + o0];
            const float4 g4 = *(const float4*)&gm2T[g * kD + o0];
#pragma unroll
            for (int r = 0; r < 4; ++r)
                vv[nt][r] = xv[nt][r] + (&g4.x)[r] * (acc2[nt][r] + (&b4.x)[r]);
        }
#pragma unroll
        for (int r = 0; r < 4; ++r) {
            float sq = vv[0][r] * vv[0][r] + vv[1][r] * vv[1][r];
#pragma unroll
            for (int off = 1; off < 16; off <<= 1) sq += __shfl_xor(sq, off, 64);
            float rn = 1.f / (sqrtf(sq) + 1e-6f);
#pragma unroll
            for (int nt = 0; nt < 2; ++nt) {
                float x = vv[nt][r] * rn;
                yv[nt][r] = x;
                s2 += x; ss2 = fmaf(x, x, ss2);
            }
        }
#pragma unroll
        for (int nt = 0; nt < 2; ++nt) {
            int g = nt * 16 + l16;
            float4 xo;
#pragma unroll
            for (int r = 0; r < 4; ++r) (&xo.x)[r] = yv[nt][r];
            *(float4*)&XT[tb + g * kD + o0] = xo;
        }
    }
    if constexpr (LAST) return;

#pragma unroll
    for (int off = 1; off < 64; off <<= 1) {
        s2 += __shfl_xor(s2, off, 64); ss2 += __shfl_xor(ss2, off, 64);
    }
    if (lane == 0) { sred[w] = s2; sred[4 + w] = ss2; }
    __syncthreads();                          // B4
    {
        float st = sred[0] + sred[1] + sred[2] + sred[3];
        float sst = sred[4] + sred[5] + sred[6] + sred[7];
        float mean = st * (1.f / kDG);
        float var  = sst * (1.f / kDG) - mean * mean;
        float rstd = rsqrtf(var + 1e-5f);
#pragma unroll
        for (int nt = 0; nt < 2; ++nt) {
            int g = nt * 16 + l16;
            short4 s4;
#pragma unroll
            for (int r = 0; r < 4; ++r)
                (&s4.x)[r] = f2bf((yv[nt][r] - mean) * rstd * (&lw1[nt].x)[r] + (&lb1[nt].x)[r]);
            *(short4*)&sA[g * AS + o0] = s4;
        }
    }
    __syncthreads();                          // B5

    // ---- phase 5: QKV(next) from sA with prefetched wqf + biases ----
    {
        bf16x8 afrA[2][2];
#pragma unroll
        for (int c = 0; c < 2; ++c)
#pragma unroll
            for (int nt = 0; nt < 2; ++nt)
                afrA[c][nt] = *(const bf16x8*)&sA[(nt * 16 + l16) * AS + c * 32 + quad * 8];

        const float4* Bp[3][2] = {{&pbq[0], &pbq[1]}, {&pbk[0], &pbk[1]}, {&pbv[0], &pbv[1]}};
        unsigned short* Op[3] = {Q, K, V};
#pragma unroll
        for (int m = 0; m < 3; ++m) {
            f32x4 acc3[2];
#pragma unroll
            for (int nt = 0; nt < 2; ++nt) acc3[nt] = (f32x4){0.f, 0.f, 0.f, 0.f};
#pragma unroll
            for (int c = 0; c < 2; ++c)
#pragma unroll
                for (int nt = 0; nt < 2; ++nt)
                    acc3[nt] = __builtin_amdgcn_mfma_f32_16x16x32_bf16(wqf[m * 2 + c], afrA[c][nt], acc3[nt], 0, 0, 0);
            unsigned short* op = Op[m] + tb;
#pragma unroll
            for (int nt = 0; nt < 2; ++nt) {
                int g = nt * 16 + l16;
                const float4 b4 = *Bp[m][nt];
#pragma unroll
                for (int r = 0; r < 4; ++r)
                    op[(o0 + r) * kG + g] = (unsigned short)f2bf(acc3[nt][r] + (&b4.x)[r]);
            }
        }
    }
}

// ---------------- Q/K/V GEMM for layer 0 only ----------------
__global__ __launch_bounds__(256, 3) void gemm_qkv_kernel(
    const unsigned short* __restrict__ X,
    const unsigned short* __restrict__ Wqh, const unsigned short* __restrict__ Wkh,
    const unsigned short* __restrict__ Wvh,
    const float* __restrict__ bqT, const float* __restrict__ bkT, const float* __restrict__ bvT,
    unsigned short* __restrict__ Q, unsigned short* __restrict__ K, unsigned short* __restrict__ V) {
    constexpr int WS = 64 + 8;
    __shared__ short sW[3 * 64 * WS];

    const int tid = threadIdx.x, wave = tid >> 6, lane = tid & 63;
    const int l16 = lane & 15, quad = lane >> 4;
    const int tok = blockIdx.x * 4 + wave;

    const unsigned short* Wp[3] = {Wqh, Wkh, Wvh};
#pragma unroll
    for (int w = 0; w < 3; ++w)
        for (int j = tid * 8; j < 64 * 64; j += 2048) {
            int o = j >> 6, i = j & 63;
            *(bf16x8*)&sW[w * 64 * WS + o * WS + i] = *(const bf16x8*)(Wp[w] + j);
        }

    const unsigned short* xp = X + (size_t)tok * kDG;
    bf16x8 bfr[2][2];
#pragma unroll
    for (int c = 0; c < 2; ++c)
#pragma unroll
        for (int nt = 0; nt < 2; ++nt)
            bfr[c][nt] = *(const bf16x8*)&xp[(nt * 16 + l16) * kD + c * 32 + quad * 8];
    __syncthreads();

    f32x4 acc[3][4][2];
#pragma unroll
    for (int w = 0; w < 3; ++w)
#pragma unroll
        for (int mt = 0; mt < 4; ++mt)
#pragma unroll
            for (int nt = 0; nt < 2; ++nt) acc[w][mt][nt] = (f32x4){0.f, 0.f, 0.f, 0.f};

#pragma unroll
    for (int w = 0; w < 3; ++w)
#pragma unroll
        for (int mt = 0; mt < 4; ++mt)
#pragma unroll
            for (int c = 0; c < 2; ++c) {
                bf16x8 afr = *(const bf16x8*)&sW[w * 64 * WS + (mt * 16 + l16) * WS + c * 32 + quad * 8];
#pragma unroll
                for (int nt = 0; nt < 2; ++nt)
                    acc[w][mt][nt] = __builtin_amdgcn_mfma_f32_16x16x32_bf16(afr, bfr[c][nt], acc[w][mt][nt], 0, 0, 0);
            }

    unsigned short* Op[3] = {Q, K, V};
    const float* Bp[3] = {bqT, bkT, bvT};
#pragma unroll
    for (int w = 0; w < 3; ++w) {
        unsigned short* op = Op[w] + (size_t)tok * kDG;
#pragma unroll
        for (int mt = 0; mt < 4; ++mt)
#pragma unroll
            for (int nt = 0; nt < 2; ++nt) {
                int g = nt * 16 + l16;
                int o0 = mt * 16 + quad * 4;
                const float4 b4 = *(const float4*)&Bp[w][g * kD + o0];
#pragma unroll
                for (int r = 0; r < 4; ++r)
                    op[(o0 + r) * kG + g] = (unsigned short)f2bf(acc[w][mt][nt][r] + (&b4.x)[r]);
            }
    }
}

// ---------------- MFMA attention: R8 structure + direct-global Q -----------
// K stays LDS-staged + double-buffered (R10 showed direct-K loses: 2x L2
// traffic). Q rows are wave-private -> load fragments straight from global,
// deleting the Q LDS roundtrip; afrag no longer depends on the first barrier.
constexpr int QSTR = 264;
constexpr int VSTR = 40;

__global__ __launch_bounds__(128) void attn_mfma_kernel(const unsigned short* __restrict__ Q,
                                                        const unsigned short* __restrict__ K,
                                                        const unsigned short* __restrict__ V,
                                                        unsigned short* __restrict__ O) {
    __shared__ short sP[32 * QSTR];          // 16.9 KB: P tile (same-wave use)
    __shared__ short sKV[2][256 * VSTR];     // 41 KB: K tiles / V^T double buffer

    const int qt = blockIdx.x, h = blockIdx.y, b = blockIdx.z;
    const int tid = threadIdx.x;
    const int wave = tid >> 6, lane = tid & 63;
    const int l16 = lane & 15, quad = lane >> 4;

    const size_t bh = (size_t)b * kS * kDG + (size_t)h * kHD;

    // Q fragments: direct from global (wave-private rows, L2-hot)
    bf16x8 afrag[8];
    {
        const unsigned short* qp = Q + bh + (size_t)(qt * 32 + wave * 16 + l16) * kDG;
#pragma unroll
        for (int c = 0; c < 8; ++c)
            afrag[c] = *(const bf16x8*)(qp + c * 32 + quad * 8);
    }

    // stage K tile 0
#pragma unroll
    for (int it = 0; it < 8; ++it) {
        int j = it * 1024 + tid * 8;
        int row = j >> 8, col = j & 255;
        *(bf16x8*)&sKV[0][row * QSTR + col] =
            *(const bf16x8*)(K + bh + (size_t)row * kDG + col);
    }
    __syncthreads();

    f32x4 acc[16];
#pragma unroll
    for (int i = 0; i < 16; ++i) acc[i] = (f32x4){0.f, 0.f, 0.f, 0.f};

    for (int kt = 0; kt < 8; ++kt) {
        bf16x8 kpre[8];
        if (kt < 7) {
#pragma unroll
            for (int it = 0; it < 8; ++it) {
                int j = it * 1024 + tid * 8;
                int row = j >> 8, col = j & 255;
                kpre[it] = *(const bf16x8*)(K + bh + (size_t)((kt + 1) * 32 + row) * kDG + col);
            }
        }
        const short* kb = sKV[kt & 1];
#pragma unroll
        for (int nt = 0; nt < 2; ++nt) {
            int key = nt * 16 + l16;
            f32x4 a = acc[kt * 2 + nt];
#pragma unroll
            for (int c = 0; c < 8; ++c) {
                bf16x8 bfrag = *(const bf16x8*)&kb[key * QSTR + c * 32 + quad * 8];
                a = __builtin_amdgcn_mfma_f32_16x16x32_bf16(afrag[c], bfrag, a, 0, 0, 0);
            }
            acc[kt * 2 + nt] = a;
        }
        if (kt < 7) {
            short* nb = sKV[(kt + 1) & 1];
#pragma unroll
            for (int it = 0; it < 8; ++it) {
                int j = it * 1024 + tid * 8;
                int row = j >> 8, col = j & 255;
                *(bf16x8*)&nb[row * QSTR + col] = kpre[it];
            }
            __syncthreads();
        }
    }

    // softmax over 256 keys (rows = quad*4 + r)
    float inv[4];
#pragma unroll
    for (int r = 0; r < 4; ++r) {
        float m = -1e30f;
#pragma unroll
        for (int t = 0; t < 16; ++t) m = fmaxf(m, acc[t][r]);
#pragma unroll
        for (int off = 1; off < 16; off <<= 1) m = fmaxf(m, __shfl_xor(m, off, 16));
        float s = 0.f;
#pragma unroll
        for (int t = 0; t < 16; ++t) {
            float p = __expf((acc[t][r] - m) * 0.0625f);
            acc[t][r] = p; s += p;
        }
#pragma unroll
        for (int off = 1; off < 16; off <<= 1) s += __shfl_xor(s, off, 16);
        inv[r] = 1.f / s;
    }

    // P (bf16) into sP — each wave writes/reads only its own 16 rows
#pragma unroll
    for (int t = 0; t < 16; ++t)
#pragma unroll
        for (int r = 0; r < 4; ++r)
            sP[(wave * 16 + quad * 4 + r) * QSTR + t * 16 + l16] = f2bf(acc[t][r]);

    // V^T tile 0 into buf 0 (128-thr gather-transpose)
    {
        const int db = tid & 63, kh = tid >> 6;
        short4 vr[16];
#pragma unroll
        for (int r = 0; r < 16; ++r)
            vr[r] = *(const short4*)(V + bh + (size_t)(kh * 16 + r) * kDG + db * 4);
#pragma unroll
        for (int i = 0; i < 4; ++i)
#pragma unroll
            for (int gq = 0; gq < 4; ++gq) {
                short4 p = make_short4((&vr[gq * 4 + 0].x)[i], (&vr[gq * 4 + 1].x)[i],
                                       (&vr[gq * 4 + 2].x)[i], (&vr[gq * 4 + 3].x)[i]);
                *(short4*)&sKV[0][(db * 4 + i) * VSTR + kh * 16 + gq * 4] = p;
            }
    }
    __syncthreads();

    f32x4 oacc[16];
#pragma unroll
    for (int i = 0; i < 16; ++i) oacc[i] = (f32x4){0.f, 0.f, 0.f, 0.f};

    for (int vt = 0; vt < 8; ++vt) {
        short4 vpre[16];
        if (vt < 7) {
            const int db = tid & 63, kh = tid >> 6;
#pragma unroll
            for (int r = 0; r < 16; ++r)
                vpre[r] = *(const short4*)(V + bh + (size_t)((vt + 1) * 32 + kh * 16 + r) * kDG + db * 4);
        }
        const short* vb = sKV[vt & 1];
        bf16x8 pfrag = *(const bf16x8*)&sP[(wave * 16 + l16) * QSTR + vt * 32 + quad * 8];
#pragma unroll
        for (int dt = 0; dt < 16; ++dt) {
            bf16x8 vfrag = *(const bf16x8*)&vb[(dt * 16 + l16) * VSTR + quad * 8];
            oacc[dt] = __builtin_amdgcn_mfma_f32_16x16x32_bf16(pfrag, vfrag, oacc[dt], 0, 0, 0);
        }
        if (vt < 7) {
            const int db = tid & 63, kh = tid >> 6;
            short* nb = sKV[(vt + 1) & 1];
#pragma unroll
            for (int i = 0; i < 4; ++i)
#pragma unroll
                for (int gq = 0; gq < 4; ++gq) {
                    short4 p = make_short4((&vpre[gq * 4 + 0].x)[i], (&vpre[gq * 4 + 1].x)[i],
                                           (&vpre[gq * 4 + 2].x)[i], (&vpre[gq * 4 + 3].x)[i]);
                    *(short4*)&nb[(db * 4 + i) * VSTR + kh * 16 + gq * 4] = p;
                }
            __syncthreads();
        }
    }

    // O write: bf16 T-layout [tok][g*64 + h*8 + dl]
    {
        const size_t ob = (size_t)(b * kS + qt * 32 + wave * 16 + quad * 4) * kDG + h * 8;
#pragma unroll
        for (int gg = 0; gg < 2; ++gg) {
            int g = gg * 16 + l16;
#pragma unroll
            for (int r = 0; r < 4; ++r) {
                bf16x8 pk;
#pragma unroll
                for (int k = 0; k < 8; ++k)
                    pk[k] = f2bf(oacc[k * 2 + gg][r] * inv[r]);
                *(bf16x8*)&O[ob + (size_t)r * kDG + g * kD] = pk;
            }
        }
    }
}

// ---------------- in-thread geometric product with compile-time signs -------
constexpr int pc_ce(unsigned v) { int c = 0; while (v) { c += v & 1; v >>= 1; } return c; }
constexpr unsigned gp_mask_ce(int a) {
    unsigned m = 0;
    for (int c = 0; c < 32; ++c) {
        int b = a ^ c;
        int s = (a & b) >> 4;
        for (int t = a >> 1; t; t >>= 1) s += pc_ce(t & b);
        if (s & 1) m |= (1u << c);
    }
    return m;
}

template<int A>
__device__ __forceinline__ void gp_term(const float* x, const float* y, float* acc) {
    constexpr unsigned m = gp_mask_ce(A);
    const float xa = x[A], nxa = -xa;
#pragma unroll
    for (int c = 0; c < 32; ++c)
        acc[c] = fmaf(((m >> c) & 1u) ? nxa : xa, y[A ^ c], acc[c]);
}

__device__ __forceinline__ void gp_mn_t(const float* x, const float* y, float* out) {
    float acc[32];
#pragma unroll
    for (int c = 0; c < 32; ++c) acc[c] = 0.f;
    gp_term<0>(x, y, acc);  gp_term<1>(x, y, acc);  gp_term<2>(x, y, acc);  gp_term<3>(x, y, acc);
    gp_term<4>(x, y, acc);  gp_term<5>(x, y, acc);  gp_term<6>(x, y, acc);  gp_term<7>(x, y, acc);
    gp_term<8>(x, y, acc);  gp_term<9>(x, y, acc);  gp_term<10>(x, y, acc); gp_term<11>(x, y, acc);
    gp_term<12>(x, y, acc); gp_term<13>(x, y, acc); gp_term<14>(x, y, acc); gp_term<15>(x, y, acc);
    gp_term<16>(x, y, acc); gp_term<17>(x, y, acc); gp_term<18>(x, y, acc); gp_term<19>(x, y, acc);
    gp_term<20>(x, y, acc); gp_term<21>(x, y, acc); gp_term<22>(x, y, acc); gp_term<23>(x, y, acc);
    gp_term<24>(x, y, acc); gp_term<25>(x, y, acc); gp_term<26>(x, y, acc); gp_term<27>(x, y, acc);
    gp_term<28>(x, y, acc); gp_term<29>(x, y, acc); gp_term<30>(x, y, acc); gp_term<31>(x, y, acc);
    float ss = 0.f;
#pragma unroll
    for (int c = 0; c < 32; ++c) ss = fmaf(acc[c], acc[c], ss);
    float r = 1.f / (sqrtf(ss) + 1e-6f);
#pragma unroll
    for (int c = 0; c < 32; ++c) out[c] = acc[c] * r;
}

__device__ __forceinline__ void leaf_load(const float* base, float* v) {
#pragma unroll
    for (int i = 0; i < 8; ++i) {
        const float4 f = *(const float4*)(base + i * 4);
        v[i * 4 + 0] = 0.5f * f.x; v[i * 4 + 1] = 0.5f * f.y;
        v[i * 4 + 2] = 0.5f * f.z; v[i * 4 + 3] = 0.5f * f.w;
    }
    v[0] += 1.f;
    float ss = 0.f;
#pragma unroll
    for (int c = 0; c < 32; ++c) ss = fmaf(v[c], v[c], ss);
    float r = 1.f / (sqrtf(ss) + 1e-6f);
#pragma unroll
    for (int c = 0; c < 32; ++c) v[c] *= r;
}

// ---------------- scan: 1 wave per sequence, 1 block per wave ---------------
__global__ __launch_bounds__(64) void scanreg_kernel(const float* __restrict__ DT,
                                                     float* __restrict__ pooled) {
    const int lane = threadIdx.x & 63;
    const int seq = blockIdx.x;
    const float* base = DT + ((size_t)seq * kS + lane * 4) * kG;

    float R[32], Y[32], P[32], Xa[32], Yb[32];

    leaf_load(base, R);
    for (int j = 1; j < 4; ++j) {
        leaf_load(base + j * kG, Y);
        gp_mn_t(Y, R, R);
    }

    for (int step = 1; step < 64; step <<= 1) {
        const bool up = lane & step;
#pragma unroll
        for (int c = 0; c < 32; ++c) P[c] = __shfl_xor(R[c], step, 64);
#pragma unroll
        for (int c = 0; c < 32; ++c) {
            Xa[c] = up ? R[c] : P[c];
            Yb[c] = up ? P[c] : R[c];
        }
        gp_mn_t(Xa, Yb, R);
    }

    if (lane == 0) {
        float* op = pooled + (size_t)seq * kG;
#pragma unroll
        for (int i = 0; i < 8; ++i)
            *(float4*)(op + i * 4) = make_float4(R[i * 4], R[i * 4 + 1], R[i * 4 + 2], R[i * 4 + 3]);
    }
}

// ---------------- classifier ----------------
__global__ __launch_bounds__(256) void cls2_kernel(const float* __restrict__ P,
                                                   const float* __restrict__ Wc,
                                                   const float* __restrict__ bc,
                                                   float* __restrict__ out) {
    __shared__ float sp[kB * kDG];
    const int tid = threadIdx.x, wave = tid >> 6, lane = tid & 63;
    for (int j = tid * 4; j < kB * kDG; j += 1024)
        *(float4*)&sp[j] = *(const float4*)(P + j);
    __syncthreads();

    const int c = blockIdx.x * 4 + wave;
    const float* w = Wc + (size_t)c * kDG;
    float acc[kB];
#pragma unroll
    for (int b = 0; b < kB; ++b) acc[b] = 0.f;
#pragma unroll
    for (int cc = 0; cc < 8; ++cc) {
        const float4 w4 = *(const float4*)(w + cc * 256 + lane * 4);
#pragma unroll
        for (int b = 0; b < kB; ++b) {
            const float4 p4 = *(const float4*)&sp[b * kDG + cc * 256 + lane * 4];
            acc[b] += w4.x * p4.x + w4.y * p4.y + w4.z * p4.z + w4.w * p4.w;
        }
    }
#pragma unroll
    for (int b = 0; b < kB; ++b)
#pragma unroll
        for (int off = 32; off > 0; off >>= 1) acc[b] += __shfl_xor(acc[b], off, 64);
    if (lane == 0) {
        float bias = bc[c];
#pragma unroll
        for (int b = 0; b < kB; ++b) out[b * kNC + c] = acc[b] + bias;
    }
}

extern "C" void kernel_launch(void* const* d_in, const int* in_sizes, int n_in,
                              void* d_out, int out_size, void* d_ws, size_t ws_size,
                              hipStream_t stream) {
    const float* x_in = (const float*)d_in[0];
    const float* Wq   = (const float*)d_in[1];
    const float* bq   = (const float*)d_in[2];
    const float* Wk   = (const float*)d_in[3];
    const float* bk   = (const float*)d_in[4];
    const float* Wv   = (const float*)d_in[5];
    const float* bv   = (const float*)d_in[6];
    const float* Wo   = (const float*)d_in[7];
    const float* bo   = (const float*)d_in[8];
    const float* ln1w = (const float*)d_in[9];
    const float* ln1b = (const float*)d_in[10];
    const float* ln2w = (const float*)d_in[11];
    const float* ln2b = (const float*)d_in[12];
    const float* gm1  = (const float*)d_in[13];
    const float* gm2  = (const float*)d_in[14];
    const float* W1   = (const float*)d_in[15];
    const float* b1   = (const float*)d_in[16];
    const float* W2   = (const float*)d_in[17];
    const float* b2   = (const float*)d_in[18];
    const float* Wr   = (const float*)d_in[19];
    const float* br   = (const float*)d_in[20];
    const float* Wc   = (const float*)d_in[21];
    const float* bc   = (const float*)d_in[22];

    const size_t NEL = (size_t)kT * kDG;
    float* F  = (float*)d_ws;
    float* XT = F;                                   // region 0: fp32 residual, T-layout
    unsigned short* Abf = (unsigned short*)(F + NEL);// region 1: attn in (A) / attn out (O)
    unsigned short* Qh = (unsigned short*)(F + 2 * NEL);
    unsigned short* Kh = (unsigned short*)(F + 3 * NEL);
    unsigned short* Vh = (unsigned short*)(F + 4 * NEL);
    unsigned short* Wb = (unsigned short*)(F + 5 * NEL);   // bf16 weights (384 KB)
    float* PT = F + 3 * NEL + NEL / 2;               // T-params (480 KB, gap after Kh)
    float* pooled = F + 2 * NEL;
    float* DT = F + NEL;

    cvtw_kernel<<<192, 256, 0, stream>>>(Wq, Wk, Wv, Wo, W1, W2, Wb);
    prep_tr_kernel<<<48, 256, 0, stream>>>(bq, bk, bv, bo, b2, gm1, gm2,
                                           ln2w, ln2b, ln1w, ln1b, b1, PT);
    unsigned short* Wqh = Wb;
    unsigned short* Wkh = Wb + 16384;
    unsigned short* Wvh = Wb + 32768;
    unsigned short* Woh = Wb + 49152;
    unsigned short* W1h = Wb + 65536;
    unsigned short* W2h = Wb + 131072;

    auto bqT   = [&](int l) { return PT + 0     + l * 2048; };
    auto bkT   = [&](int l) { return PT + 8192  + l * 2048; };
    auto bvT   = [&](int l) { return PT + 16384 + l * 2048; };
    auto boT   = [&](int l) { return PT + 24576 + l * 2048; };
    auto b2T   = [&](int l) { return PT + 32768 + l * 2048; };
    auto gm1T  = [&](int l) { return PT + 40960 + l * 2048; };
    auto gm2T  = [&](int l) { return PT + 49152 + l * 2048; };
    auto ln2wT = [&](int l) { return PT + 57344 + l * 2048; };
    auto ln2bT = [&](int l) { return PT + 65536 + l * 2048; };
    auto ln1wT = [&](int l) { return PT + 73728 + l * 2048; };
    auto ln1bT = [&](int l) { return PT + 81920 + l * 2048; };
    auto b1T   = [&](int l) { return PT + 90112 + l * 8192; };

    ln_kernel<<<kT, 256, 0, stream>>>(x_in, ln1w, ln1b, Abf, XT);
    gemm_qkv_kernel<<<kT / 4, 256, 0, stream>>>(Abf,
        Wqh, Wkh, Wvh, bqT(0), bkT(0), bvT(0), Qh, Kh, Vh);

    for (int l = 0; l < 4; l++) {
        attn_mfma_kernel<<<dim3(8, kNH, kB), 128, 0, stream>>>(Qh, Kh, Vh, Abf);
        if (l < 3)
            mega_kernel<false><<<kT, 256, 0, stream>>>(Abf,
                Woh + l * 4096, boT(l), gm1T(l), ln2wT(l), ln2bT(l),
                W1h + l * 16384, b1T(l), W2h + l * 16384, b2T(l), gm2T(l),
                ln1wT(l + 1), ln1bT(l + 1), XT,
                Wqh + (l + 1) * 4096, Wkh + (l + 1) * 4096, Wvh + (l + 1) * 4096,
                bqT(l + 1), bkT(l + 1), bvT(l + 1), Qh, Kh, Vh);
        else
            mega_kernel<true><<<kT, 256, 0, stream>>>(Abf,
                Woh + l * 4096, boT(l), gm1T(l), ln2wT(l), ln2bT(l),
                W1h + l * 16384, b1T(l), W2h + l * 16384, b2T(l), gm2T(l),
                nullptr, nullptr, XT,
                nullptr, nullptr, nullptr, nullptr, nullptr, nullptr,
                nullptr, nullptr, nullptr);
    }

    vlinT_kernel<<<kT, 256, 0, stream>>>(XT, Wr, br, DT);
    scanreg_kernel<<<kB * kD, 64, 0, stream>>>(DT, pooled);
    cls2_kernel<<<kNC / 4, 256, 0, stream>>>(pooled, Wc, bc, (float*)d_out);
}